// Round 1
// baseline (894.168 us; speedup 1.0000x reference)
//
#include <hip/hip_runtime.h>

#define ALPHA 0.2f
#define EPS 1e-16f

static constexpr int F_IN = 256;
static constexpr int F_OUT = 128;
static constexpr int HEADS = 4;
static constexpr int COLS = HEADS * F_OUT; // 512

// ---------------- K1: Ht[N,512] = H[N,256] @ Wcat[512,256]^T (f32, vector) ----
__global__ __launch_bounds__(256) void k_gemm(const float* __restrict__ A,
                                              const float* __restrict__ B,
                                              float* __restrict__ C, int N) {
  // 64x64 tile, BK=16, 256 threads, 4x4 micro-tile
  __shared__ float As[16][68]; // [k][m], pad to 68 (16B-aligned rows, conflict-light)
  __shared__ float Bs[16][68]; // [k][n]
  const int tid = threadIdx.x;
  const int tx = tid & 15, ty = tid >> 4;
  const int m0 = blockIdx.y << 6, n0 = blockIdx.x << 6;
  const int lr = tid >> 2;        // 0..63 row within tile
  const int lc = (tid & 3) << 2;  // 0,4,8,12 col group
  float acc[4][4] = {};
  for (int k0 = 0; k0 < F_IN; k0 += 16) {
    int ar = m0 + lr; if (ar >= N) ar = N - 1;  // clamp (stores guarded)
    const float4 av = *(const float4*)&A[(size_t)ar * F_IN + k0 + lc];
    const float4 bv = *(const float4*)&B[(size_t)(n0 + lr) * F_IN + k0 + lc];
    As[lc + 0][lr] = av.x; As[lc + 1][lr] = av.y; As[lc + 2][lr] = av.z; As[lc + 3][lr] = av.w;
    Bs[lc + 0][lr] = bv.x; Bs[lc + 1][lr] = bv.y; Bs[lc + 2][lr] = bv.z; Bs[lc + 3][lr] = bv.w;
    __syncthreads();
#pragma unroll
    for (int kk = 0; kk < 16; ++kk) {
      const float4 a4 = *(const float4*)&As[kk][ty << 2];
      const float4 b4 = *(const float4*)&Bs[kk][tx << 2];
      const float a_[4] = {a4.x, a4.y, a4.z, a4.w};
      const float b_[4] = {b4.x, b4.y, b4.z, b4.w};
#pragma unroll
      for (int i = 0; i < 4; ++i)
#pragma unroll
        for (int j = 0; j < 4; ++j) acc[i][j] = fmaf(a_[i], b_[j], acc[i][j]);
    }
    __syncthreads();
  }
#pragma unroll
  for (int i = 0; i < 4; ++i) {
    const int row = m0 + (ty << 2) + i;
    if (row < N) {
      float4 v = make_float4(acc[i][0], acc[i][1], acc[i][2], acc[i][3]);
      *(float4*)&C[(size_t)row * COLS + n0 + (tx << 2)] = v;
    }
  }
}

// ---------------- K2: per-node attention scores --------------------------------
// s_src[n,h] = Ht[n, h-block] . a[h,:128]; s_dst likewise with a[h,128:]
__global__ __launch_bounds__(256) void k_scores(const float* __restrict__ Ht,
                                                const float* __restrict__ a,
                                                float* __restrict__ ssrc,
                                                float* __restrict__ sdst, int N) {
  const int n = blockIdx.x;
  const int h = threadIdx.x >> 6;   // wave -> head
  const int lane = threadIdx.x & 63;
  const float v1 = Ht[(size_t)n * COLS + h * F_OUT + lane];
  const float v2 = Ht[(size_t)n * COLS + h * F_OUT + 64 + lane];
  const float* ah = a + h * 2 * F_OUT;
  float ss = v1 * ah[lane] + v2 * ah[64 + lane];
  float sd = v1 * ah[F_OUT + lane] + v2 * ah[F_OUT + 64 + lane];
#pragma unroll
  for (int o = 32; o > 0; o >>= 1) {
    ss += __shfl_down(ss, o);
    sd += __shfl_down(sd, o);
  }
  if (lane == 0) {
    ssrc[n * HEADS + h] = ss;
    sdst[n * HEADS + h] = sd;
  }
}

// ---------------- K3/K4/K5: build CSR grouped by src ---------------------------
__global__ void k_hist(const int* __restrict__ src, int* __restrict__ cnt, int E) {
  int i = blockIdx.x * blockDim.x + threadIdx.x;
  const int stride = gridDim.x * blockDim.x;
  for (; i < E; i += stride) atomicAdd(&cnt[src[i]], 1);
}

__global__ __launch_bounds__(1024) void k_scan(const int* __restrict__ cnt,
                                               int* __restrict__ off, int N) {
  __shared__ int buf[1024];
  __shared__ int s_carry;
  const int t = threadIdx.x;
  if (t == 0) { s_carry = 0; off[0] = 0; }
  __syncthreads();
  for (int base = 0; base < N; base += 1024) {
    buf[t] = (base + t < N) ? cnt[base + t] : 0;
    __syncthreads();
    for (int ofs = 1; ofs < 1024; ofs <<= 1) {
      const int x = (t >= ofs) ? buf[t - ofs] : 0;
      __syncthreads();
      buf[t] += x;
      __syncthreads();
    }
    const int inc = buf[t];     // inclusive prefix within chunk
    const int c = s_carry;
    if (base + t < N) off[base + t + 1] = c + inc;
    __syncthreads();
    if (t == 1023) s_carry = c + inc;
    __syncthreads();
  }
}

__global__ void k_scatter(const int* __restrict__ src, const int* __restrict__ dst,
                          const int* __restrict__ off, int* __restrict__ cur,
                          int* __restrict__ csr_dst, int E) {
  int i = blockIdx.x * blockDim.x + threadIdx.x;
  const int stride = gridDim.x * blockDim.x;
  for (; i < E; i += stride) {
    const int s = src[i];
    const int p = atomicAdd(&cur[s], 1);
    csr_dst[off[s] + p] = dst[i];
  }
}

// ---------------- K6: fused segment-softmax + SpMM, one wave per src node ------
__global__ __launch_bounds__(256) void k_spmm(const float* __restrict__ Ht,
    const float* __restrict__ ssrc, const float* __restrict__ sdst,
    const int* __restrict__ off, const int* __restrict__ csr_dst,
    const float* __restrict__ bias, float* __restrict__ out, int N) {
  const int lane = threadIdx.x & 63;
  const int n = (blockIdx.x << 2) + (threadIdx.x >> 6);
  if (n >= N) return;
  const float4 ss4 = *(const float4*)&ssrc[n * HEADS];
  const float ssv[4] = {ss4.x, ss4.y, ss4.z, ss4.w};
  float den[4]  = {0.f, 0.f, 0.f, 0.f};
  float accx[4] = {0.f, 0.f, 0.f, 0.f};
  float accy[4] = {0.f, 0.f, 0.f, 0.f};
  const int beg = off[n], end = off[n + 1];
  for (int j = beg; j < end; ++j) {
    const int d = csr_dst[j];                       // wave-uniform broadcast load
    const float4 sd4 = *(const float4*)&sdst[d * HEADS];
    const float sdv[4] = {sd4.x, sd4.y, sd4.z, sd4.w};
    const float* hrow = Ht + (size_t)d * COLS;
#pragma unroll
    for (int h = 0; h < 4; ++h) {
      float e = ssv[h] + sdv[h];
      e = e > 0.f ? e : ALPHA * e;                  // LeakyReLU
      const float w = __expf(e);                    // no max-sub needed: e bounded
      den[h] += w;
      const float2 v = *(const float2*)&hrow[h * F_OUT + (lane << 1)];
      accx[h] = fmaf(w, v.x, accx[h]);
      accy[h] = fmaf(w, v.y, accy[h]);
    }
  }
  float o0 = 0.f, o1 = 0.f;
#pragma unroll
  for (int h = 0; h < 4; ++h) {
    const float r = 1.f / (den[h] + EPS);
    o0 = fmaf(accx[h], r, o0);
    o1 = fmaf(accy[h], r, o1);
  }
  const float2 b = *(const float2*)&bias[lane << 1];
  float2 res = make_float2(0.25f * o0 + b.x, 0.25f * o1 + b.y);
  *(float2*)&out[(size_t)n * F_OUT + (lane << 1)] = res;
}

// ---------------- launch -------------------------------------------------------
extern "C" void kernel_launch(void* const* d_in, const int* in_sizes, int n_in,
                              void* d_out, int out_size, void* d_ws, size_t ws_size,
                              hipStream_t stream) {
  const float* H    = (const float*)d_in[0];
  const int*   ei   = (const int*)d_in[1];
  const float* W    = (const float*)d_in[2];   // [4,128,256] == [512,256]
  const float* a    = (const float*)d_in[3];   // [4,256]
  const float* bias = (const float*)d_in[4];   // [128]
  const int N = in_sizes[0] / F_IN;
  const int E = in_sizes[1] / 2;
  const int* src = ei;
  const int* dst = ei + E;

  char* ws = (char*)d_ws;
  size_t o = 0;
  auto alloc = [&](size_t bytes) -> void* {
    void* p = ws + o;
    o = (o + bytes + 255) & ~(size_t)255;
    return p;
  };
  float* Ht   = (float*)alloc((size_t)N * COLS * sizeof(float)); // 102.4 MB
  float* ssrc = (float*)alloc((size_t)N * HEADS * sizeof(float));
  float* sdst = (float*)alloc((size_t)N * HEADS * sizeof(float));
  int*   cnt  = (int*)alloc((size_t)N * sizeof(int));
  int*   off  = (int*)alloc(((size_t)N + 1) * sizeof(int));
  int*   cur  = (int*)alloc((size_t)N * sizeof(int));
  int*   csr  = (int*)alloc((size_t)E * sizeof(int));

  hipMemsetAsync(cnt, 0, (size_t)N * sizeof(int), stream);
  hipMemsetAsync(cur, 0, (size_t)N * sizeof(int), stream);

  dim3 ggrid(COLS / 64, (N + 63) / 64);
  k_gemm<<<ggrid, 256, 0, stream>>>(H, W, Ht, N);
  k_scores<<<N, 256, 0, stream>>>(Ht, a, ssrc, sdst, N);
  k_hist<<<1024, 256, 0, stream>>>(src, cnt, E);
  k_scan<<<1, 1024, 0, stream>>>(cnt, off, N);
  k_scatter<<<1024, 256, 0, stream>>>(src, dst, off, cur, csr, E);
  k_spmm<<<(N + 3) / 4, 256, 0, stream>>>(Ht, ssrc, sdst, off, csr, bias, (float*)d_out, N);
}

// Round 2
// 570.092 us; speedup vs baseline: 1.5685x; 1.5685x over previous
//
#include <hip/hip_runtime.h>

#define ALPHA 0.2f
#define EPS 1e-16f

static constexpr int F_IN = 256;
static constexpr int F_OUT = 128;
static constexpr int HEADS = 4;
static constexpr int COLS = HEADS * F_OUT; // 512

typedef __bf16 bf16x8 __attribute__((ext_vector_type(8)));
typedef float f32x4 __attribute__((ext_vector_type(4)));

static __device__ __forceinline__ unsigned short f2bf(float f) {
  unsigned int u = __float_as_uint(f);
  unsigned int r = (u + 0x7FFFu + ((u >> 16) & 1u)) >> 16;  // RN-even
  return (unsigned short)r;
}
static __device__ __forceinline__ float bf2f(unsigned short s) {
  return __uint_as_float(((unsigned int)s) << 16);
}

// ---------------- K0: f32 -> bf16 cast (vectorized) ---------------------------
__global__ void k_cast(const float* __restrict__ x, unsigned short* __restrict__ y, int n4) {
  int i = blockIdx.x * blockDim.x + threadIdx.x;
  const int stride = gridDim.x * blockDim.x;
  for (; i < n4; i += stride) {
    const float4 v = ((const float4*)x)[i];
    ((ushort4*)y)[i] = make_ushort4(f2bf(v.x), f2bf(v.y), f2bf(v.z), f2bf(v.w));
  }
}

// ---------------- K1: Ht_bf16[N,512] = Hb[N,256] @ Wb[512,256]^T via MFMA -----
__global__ __launch_bounds__(256) void k_gemm_bf16(const unsigned short* __restrict__ A,
                                                   const unsigned short* __restrict__ B,
                                                   unsigned short* __restrict__ C, int N) {
  // 128(M) x 64(N) tile, BK=32, 4 waves; each wave 32x64 via 2x4 16x16 frags
  __shared__ __bf16 As[128][40];  // pad 32->40: 80B rows, 16B-aligned, 2-way reads (free)
  __shared__ __bf16 Bs[64][40];
  const int t = threadIdx.x;
  const int w = t >> 6, l = t & 63;
  const int m0 = blockIdx.y << 7, n0 = blockIdx.x << 6;
  const int lr = t >> 2, seg = (t & 3) << 3;  // staging: row, 8-elem col group
  f32x4 acc[2][4] = {};
  for (int k0 = 0; k0 < F_IN; k0 += 32) {
    int ar0 = m0 + lr;      if (ar0 >= N) ar0 = N - 1;   // clamp; stores guarded
    int ar1 = m0 + lr + 64; if (ar1 >= N) ar1 = N - 1;
    const uint4 a0 = *(const uint4*)&A[(size_t)ar0 * F_IN + k0 + seg];
    const uint4 a1 = *(const uint4*)&A[(size_t)ar1 * F_IN + k0 + seg];
    const uint4 b0 = *(const uint4*)&B[(size_t)(n0 + lr) * F_IN + k0 + seg];
    __syncthreads();            // prior iter's reads done before overwrite
    *(uint4*)&As[lr][seg] = a0;
    *(uint4*)&As[lr + 64][seg] = a1;
    *(uint4*)&Bs[lr][seg] = b0;
    __syncthreads();
    const int kb = (l >> 4) << 3;   // k-subblock of 8 per lane-quarter
    bf16x8 af[2], bfr[4];
#pragma unroll
    for (int mi = 0; mi < 2; ++mi)
      af[mi] = *(const bf16x8*)&As[(w << 5) + (mi << 4) + (l & 15)][kb];
#pragma unroll
    for (int ni = 0; ni < 4; ++ni)
      bfr[ni] = *(const bf16x8*)&Bs[(ni << 4) + (l & 15)][kb];
#pragma unroll
    for (int mi = 0; mi < 2; ++mi)
#pragma unroll
      for (int ni = 0; ni < 4; ++ni)
        acc[mi][ni] = __builtin_amdgcn_mfma_f32_16x16x32_bf16(af[mi], bfr[ni], acc[mi][ni], 0, 0, 0);
  }
  // C/D layout: col = lane&15, row = (lane>>4)*4 + reg
#pragma unroll
  for (int mi = 0; mi < 2; ++mi)
#pragma unroll
    for (int r = 0; r < 4; ++r) {
      const int row = m0 + (w << 5) + (mi << 4) + ((l >> 4) << 2) + r;
      if (row < N) {
#pragma unroll
        for (int ni = 0; ni < 4; ++ni)
          C[(size_t)row * COLS + n0 + (ni << 4) + (l & 15)] = f2bf(acc[mi][ni][r]);
      }
    }
}

// ---------------- K2: per-node attention scores (bf16 Ht) ---------------------
__global__ __launch_bounds__(256) void k_scores(const unsigned short* __restrict__ Hb,
                                                const float* __restrict__ a,
                                                float* __restrict__ ssrc,
                                                float* __restrict__ sdst, int N) {
  const int n = blockIdx.x;
  const int h = threadIdx.x >> 6;
  const int lane = threadIdx.x & 63;
  const float v1 = bf2f(Hb[(size_t)n * COLS + h * F_OUT + lane]);
  const float v2 = bf2f(Hb[(size_t)n * COLS + h * F_OUT + 64 + lane]);
  const float* ah = a + h * 2 * F_OUT;
  float ss = v1 * ah[lane] + v2 * ah[64 + lane];
  float sd = v1 * ah[F_OUT + lane] + v2 * ah[F_OUT + 64 + lane];
#pragma unroll
  for (int o = 32; o > 0; o >>= 1) {
    ss += __shfl_down(ss, o);
    sd += __shfl_down(sd, o);
  }
  if (lane == 0) {
    ssrc[n * HEADS + h] = ss;
    sdst[n * HEADS + h] = sd;
  }
}

// ---------------- K3/K4/K5: build CSR grouped by src ---------------------------
__global__ void k_hist(const int* __restrict__ src, int* __restrict__ cnt, int E) {
  int i = blockIdx.x * blockDim.x + threadIdx.x;
  const int stride = gridDim.x * blockDim.x;
  for (; i < E; i += stride) atomicAdd(&cnt[src[i]], 1);
}

__global__ __launch_bounds__(1024) void k_scan(const int* __restrict__ cnt,
                                               int* __restrict__ off, int N) {
  __shared__ int buf[1024];
  __shared__ int s_carry;
  const int t = threadIdx.x;
  if (t == 0) { s_carry = 0; off[0] = 0; }
  __syncthreads();
  for (int base = 0; base < N; base += 1024) {
    buf[t] = (base + t < N) ? cnt[base + t] : 0;
    __syncthreads();
    for (int ofs = 1; ofs < 1024; ofs <<= 1) {
      const int x = (t >= ofs) ? buf[t - ofs] : 0;
      __syncthreads();
      buf[t] += x;
      __syncthreads();
    }
    const int inc = buf[t];
    const int c = s_carry;
    if (base + t < N) off[base + t + 1] = c + inc;
    __syncthreads();
    if (t == 1023) s_carry = c + inc;
    __syncthreads();
  }
}

__global__ void k_scatter(const int* __restrict__ src, const int* __restrict__ dst,
                          const int* __restrict__ off, int* __restrict__ cur,
                          int* __restrict__ csr_dst, int E) {
  int i = blockIdx.x * blockDim.x + threadIdx.x;
  const int stride = gridDim.x * blockDim.x;
  for (; i < E; i += stride) {
    const int s = src[i];
    const int p = atomicAdd(&cur[s], 1);
    csr_dst[off[s] + p] = dst[i];
  }
}

// ---------------- K6: fused segment-softmax + SpMM (bf16 gather) ---------------
__global__ __launch_bounds__(256) void k_spmm(const unsigned int* __restrict__ Hb32,
    const float* __restrict__ ssrc, const float* __restrict__ sdst,
    const int* __restrict__ off, const int* __restrict__ csr_dst,
    const float* __restrict__ bias, float* __restrict__ out, int N) {
  const int lane = threadIdx.x & 63;
  const int n = (blockIdx.x << 2) + (threadIdx.x >> 6);
  if (n >= N) return;
  const float4 ss4 = *(const float4*)&ssrc[n * HEADS];
  const float ssv[4] = {ss4.x, ss4.y, ss4.z, ss4.w};
  float den[4]  = {0.f, 0.f, 0.f, 0.f};
  float accx[4] = {0.f, 0.f, 0.f, 0.f};
  float accy[4] = {0.f, 0.f, 0.f, 0.f};
  const int beg = off[n], end = off[n + 1];
  for (int j = beg; j < end; ++j) {
    const int d = csr_dst[j];                        // wave-uniform broadcast
    const float4 sd4 = *(const float4*)&sdst[d * HEADS];
    const float sdv[4] = {sd4.x, sd4.y, sd4.z, sd4.w};
    const unsigned int* hrow = Hb32 + (size_t)d * (COLS / 2);
#pragma unroll
    for (int h = 0; h < 4; ++h) {
      float e = ssv[h] + sdv[h];
      e = e > 0.f ? e : ALPHA * e;                   // LeakyReLU
      const float wgt = __expf(e);                   // bounded e: no max-sub needed
      den[h] += wgt;
      const unsigned int v = hrow[h * (F_OUT / 2) + lane];  // 2 bf16, coalesced
      const float vx = __uint_as_float(v << 16);
      const float vy = __uint_as_float(v & 0xFFFF0000u);
      accx[h] = fmaf(wgt, vx, accx[h]);
      accy[h] = fmaf(wgt, vy, accy[h]);
    }
  }
  float o0 = 0.f, o1 = 0.f;
#pragma unroll
  for (int h = 0; h < 4; ++h) {
    const float r = 1.f / (den[h] + EPS);
    o0 = fmaf(accx[h], r, o0);
    o1 = fmaf(accy[h], r, o1);
  }
  const float2 b = *(const float2*)&bias[lane << 1];
  *(float2*)&out[(size_t)n * F_OUT + (lane << 1)] =
      make_float2(0.25f * o0 + b.x, 0.25f * o1 + b.y);
}

// ---------------- launch -------------------------------------------------------
extern "C" void kernel_launch(void* const* d_in, const int* in_sizes, int n_in,
                              void* d_out, int out_size, void* d_ws, size_t ws_size,
                              hipStream_t stream) {
  const float* H    = (const float*)d_in[0];
  const int*   ei   = (const int*)d_in[1];
  const float* W    = (const float*)d_in[2];   // [4,128,256] == [512,256]
  const float* a    = (const float*)d_in[3];   // [4,256]
  const float* bias = (const float*)d_in[4];   // [128]
  const int N = in_sizes[0] / F_IN;
  const int E = in_sizes[1] / 2;
  const int* src = ei;
  const int* dst = ei + E;

  char* ws = (char*)d_ws;
  size_t o = 0;
  auto alloc = [&](size_t bytes) -> void* {
    void* p = ws + o;
    o = (o + bytes + 255) & ~(size_t)255;
    return p;
  };
  unsigned short* Hb  = (unsigned short*)alloc((size_t)N * F_IN * sizeof(unsigned short));
  unsigned short* Wb  = (unsigned short*)alloc((size_t)COLS * F_IN * sizeof(unsigned short));
  unsigned short* Ht  = (unsigned short*)alloc((size_t)N * COLS * sizeof(unsigned short)); // 51 MB
  float* ssrc = (float*)alloc((size_t)N * HEADS * sizeof(float));
  float* sdst = (float*)alloc((size_t)N * HEADS * sizeof(float));
  int*   cnt  = (int*)alloc((size_t)N * sizeof(int));
  int*   off  = (int*)alloc(((size_t)N + 1) * sizeof(int));
  int*   cur  = (int*)alloc((size_t)N * sizeof(int));
  int*   csr  = (int*)alloc((size_t)E * sizeof(int));

  hipMemsetAsync(cnt, 0, (size_t)N * sizeof(int), stream);
  hipMemsetAsync(cur, 0, (size_t)N * sizeof(int), stream);

  k_cast<<<2048, 256, 0, stream>>>(H, Hb, N * F_IN / 4);
  k_cast<<<128, 256, 0, stream>>>(W, Wb, COLS * F_IN / 4);

  dim3 ggrid(COLS / 64, (N + 127) / 128);
  k_gemm_bf16<<<ggrid, 256, 0, stream>>>(Hb, Wb, Ht, N);
  k_scores<<<N, 256, 0, stream>>>(Ht, a, ssrc, sdst, N);
  k_hist<<<1024, 256, 0, stream>>>(src, cnt, E);
  k_scan<<<1, 1024, 0, stream>>>(cnt, off, N);
  k_scatter<<<1024, 256, 0, stream>>>(src, dst, off, cur, csr, E);
  k_spmm<<<(N + 3) / 4, 256, 0, stream>>>((const unsigned int*)Ht, ssrc, sdst, off, csr, bias,
                                          (float*)d_out, N);
}

// Round 3
// 471.412 us; speedup vs baseline: 1.8968x; 1.2093x over previous
//
#include <hip/hip_runtime.h>

#define ALPHA 0.2f
#define EPS 1e-16f

static constexpr int F_IN = 256;
static constexpr int F_OUT = 128;
static constexpr int HEADS = 4;
static constexpr int COLS = HEADS * F_OUT; // 512

typedef __bf16 bf16x8 __attribute__((ext_vector_type(8)));
typedef float f32x4 __attribute__((ext_vector_type(4)));

static __device__ __forceinline__ unsigned short f2bf(float f) {
  unsigned int u = __float_as_uint(f);
  unsigned int r = (u + 0x7FFFu + ((u >> 16) & 1u)) >> 16;  // RN-even
  return (unsigned short)r;
}
static __device__ __forceinline__ float bf_lo(unsigned int u) {
  return __uint_as_float(u << 16);
}
static __device__ __forceinline__ float bf_hi(unsigned int u) {
  return __uint_as_float(u & 0xFFFF0000u);
}

// ---------------- K0: f32 -> bf16 cast (vectorized) ---------------------------
__global__ void k_cast(const float* __restrict__ x, unsigned short* __restrict__ y, int n4) {
  int i = blockIdx.x * blockDim.x + threadIdx.x;
  const int stride = gridDim.x * blockDim.x;
  for (; i < n4; i += stride) {
    const float4 v = ((const float4*)x)[i];
    ((ushort4*)y)[i] = make_ushort4(f2bf(v.x), f2bf(v.y), f2bf(v.z), f2bf(v.w));
  }
}

// ---------------- K1: Ht_bf16[N,512] = Hb[N,256] @ Wb[512,256]^T via MFMA -----
__global__ __launch_bounds__(256) void k_gemm_bf16(const unsigned short* __restrict__ A,
                                                   const unsigned short* __restrict__ B,
                                                   unsigned short* __restrict__ C, int N) {
  // 128(M) x 64(N) tile, BK=32, 4 waves; each wave 32x64 via 2x4 16x16 frags
  __shared__ __bf16 As[128][40];
  __shared__ __bf16 Bs[64][40];
  const int t = threadIdx.x;
  const int w = t >> 6, l = t & 63;
  const int m0 = blockIdx.y << 7, n0 = blockIdx.x << 6;
  const int lr = t >> 2, seg = (t & 3) << 3;
  f32x4 acc[2][4] = {};
  for (int k0 = 0; k0 < F_IN; k0 += 32) {
    int ar0 = m0 + lr;      if (ar0 >= N) ar0 = N - 1;
    int ar1 = m0 + lr + 64; if (ar1 >= N) ar1 = N - 1;
    const uint4 a0 = *(const uint4*)&A[(size_t)ar0 * F_IN + k0 + seg];
    const uint4 a1 = *(const uint4*)&A[(size_t)ar1 * F_IN + k0 + seg];
    const uint4 b0 = *(const uint4*)&B[(size_t)(n0 + lr) * F_IN + k0 + seg];
    __syncthreads();
    *(uint4*)&As[lr][seg] = a0;
    *(uint4*)&As[lr + 64][seg] = a1;
    *(uint4*)&Bs[lr][seg] = b0;
    __syncthreads();
    const int kb = (l >> 4) << 3;
    bf16x8 af[2], bfr[4];
#pragma unroll
    for (int mi = 0; mi < 2; ++mi)
      af[mi] = *(const bf16x8*)&As[(w << 5) + (mi << 4) + (l & 15)][kb];
#pragma unroll
    for (int ni = 0; ni < 4; ++ni)
      bfr[ni] = *(const bf16x8*)&Bs[(ni << 4) + (l & 15)][kb];
#pragma unroll
    for (int mi = 0; mi < 2; ++mi)
#pragma unroll
      for (int ni = 0; ni < 4; ++ni)
        acc[mi][ni] = __builtin_amdgcn_mfma_f32_16x16x32_bf16(af[mi], bfr[ni], acc[mi][ni], 0, 0, 0);
  }
#pragma unroll
  for (int mi = 0; mi < 2; ++mi)
#pragma unroll
    for (int r = 0; r < 4; ++r) {
      const int row = m0 + (w << 5) + (mi << 4) + ((l >> 4) << 2) + r;
      if (row < N) {
#pragma unroll
        for (int ni = 0; ni < 4; ++ni)
          C[(size_t)row * COLS + n0 + (ni << 4) + (l & 15)] = f2bf(acc[mi][ni][r]);
      }
    }
}

// ---------------- K2: per-node scores, vectorized: 4 nodes/block --------------
__global__ __launch_bounds__(256) void k_scores(const uint4* __restrict__ Hb4,
                                                const float* __restrict__ a,
                                                float* __restrict__ ssrc,
                                                float* __restrict__ sdst, int N) {
  const int lane = threadIdx.x & 63;
  const int n = (blockIdx.x << 2) + (threadIdx.x >> 6);
  if (n >= N) return;
  const int hg = lane >> 4;            // head of this lane
  const int f0 = (lane & 15) << 3;     // feature base within head
  const uint4 v = Hb4[(size_t)n * 64 + lane];
  const unsigned int vu[4] = {v.x, v.y, v.z, v.w};
  const float* ah = a + hg * 2 * F_OUT;
  float ss = 0.f, sd = 0.f;
#pragma unroll
  for (int q = 0; q < 4; ++q) {
    const float x0 = bf_lo(vu[q]), x1 = bf_hi(vu[q]);
    ss = fmaf(x0, ah[f0 + 2 * q], fmaf(x1, ah[f0 + 2 * q + 1], ss));
    sd = fmaf(x0, ah[F_OUT + f0 + 2 * q], fmaf(x1, ah[F_OUT + f0 + 2 * q + 1], sd));
  }
#pragma unroll
  for (int m = 1; m < 16; m <<= 1) {
    ss += __shfl_xor(ss, m);
    sd += __shfl_xor(sd, m);
  }
  if ((lane & 15) == 0) {
    ssrc[n * HEADS + hg] = ss;
    sdst[n * HEADS + hg] = sd;
  }
}

// ---------------- CSR build: hist + 3-phase scan + scatter --------------------
__global__ void k_hist(const int* __restrict__ src, int* __restrict__ cnt, int E) {
  int i = blockIdx.x * blockDim.x + threadIdx.x;
  const int stride = gridDim.x * blockDim.x;
  for (; i < E; i += stride) atomicAdd(&cnt[src[i]], 1);
}

__global__ __launch_bounds__(1024) void k_scan1(const int* __restrict__ cnt,
                                                int* __restrict__ part,
                                                int* __restrict__ bsum, int N) {
  __shared__ int ws[16];
  const int t = threadIdx.x, g = blockIdx.x * 1024 + t;
  const int lane = t & 63, w = t >> 6;
  int v = (g < N) ? cnt[g] : 0;
#pragma unroll
  for (int o = 1; o < 64; o <<= 1) {
    const int y = __shfl_up(v, o);
    if (lane >= o) v += y;
  }
  if (lane == 63) ws[w] = v;
  __syncthreads();
  if (w == 0) {
    int s = (lane < 16) ? ws[lane] : 0;
#pragma unroll
    for (int o = 1; o < 16; o <<= 1) {
      const int y = __shfl_up(s, o);
      if (lane >= o) s += y;
    }
    if (lane < 16) ws[lane] = s;
  }
  __syncthreads();
  v += (w > 0) ? ws[w - 1] : 0;
  if (g < N) part[g] = v;                 // inclusive within chunk
  if (t == 1023) bsum[blockIdx.x] = v;
}

__global__ void k_scan2(int* __restrict__ bsum, int nb) {
  const int lane = threadIdx.x;
  int carry = 0;
  for (int base = 0; base < nb; base += 64) {
    int v = (base + lane < nb) ? bsum[base + lane] : 0;
#pragma unroll
    for (int o = 1; o < 64; o <<= 1) {
      const int y = __shfl_up(v, o);
      if (lane >= o) v += y;
    }
    v += carry;
    if (base + lane < nb) bsum[base + lane] = v;  // inclusive
    carry = __shfl(v, 63);
  }
}

__global__ __launch_bounds__(1024) void k_scan3(const int* __restrict__ part,
                                                const int* __restrict__ bsum,
                                                int* __restrict__ off, int N) {
  const int g = blockIdx.x * 1024 + threadIdx.x;
  if (g == 0) off[0] = 0;
  if (g < N) off[g + 1] = part[g] + (blockIdx.x ? bsum[blockIdx.x - 1] : 0);
}

__global__ void k_scatter(const int* __restrict__ src, const int* __restrict__ dst,
                          const int* __restrict__ off, int* __restrict__ cur,
                          int* __restrict__ csr_dst, int E) {
  int i = blockIdx.x * blockDim.x + threadIdx.x;
  const int stride = gridDim.x * blockDim.x;
  for (; i < E; i += stride) {
    const int s = src[i];
    const int p = atomicAdd(&cur[s], 1);
    csr_dst[off[s] + p] = dst[i];
  }
}

// ---------------- K6: fused softmax + SpMM — one head per 16-lane group -------
__global__ __launch_bounds__(256) void k_spmm(const uint4* __restrict__ Hb4,
    const float* __restrict__ ssrc, const float* __restrict__ sdst,
    const int* __restrict__ off, const int* __restrict__ csr_dst,
    const float* __restrict__ bias, float* __restrict__ out, int N) {
  const int lane = threadIdx.x & 63;
  const int n = (blockIdx.x << 2) + (threadIdx.x >> 6);
  if (n >= N) return;
  const int hg = lane >> 4;            // this lane's head
  const float ss = ssrc[n * HEADS + hg];
  float den = 0.f;
  float acc[8] = {};
  const int beg = off[n], end = off[n + 1];
  for (int j = beg; j < end; ++j) {
    const int d = __builtin_amdgcn_readfirstlane(csr_dst[j]);  // scalar base
    const float sd = sdst[d * HEADS + hg];
    float e = ss + sd;
    e = fmaxf(e, ALPHA * e);                    // LeakyReLU (alpha<1)
    const float wgt = __expf(e);                // bounded e: no max-sub needed
    den += wgt;
    const uint4 v = Hb4[(size_t)d * 64 + lane]; // whole 1KB row per wave
    const unsigned int vu[4] = {v.x, v.y, v.z, v.w};
#pragma unroll
    for (int q = 0; q < 4; ++q) {
      acc[2 * q]     = fmaf(wgt, bf_lo(vu[q]), acc[2 * q]);
      acc[2 * q + 1] = fmaf(wgt, bf_hi(vu[q]), acc[2 * q + 1]);
    }
  }
  const float r = 1.f / (den + EPS);
#pragma unroll
  for (int i = 0; i < 8; ++i) acc[i] *= r;
  // combine the 4 heads: lanes l, l^16, l^32, l^48 hold same features
#pragma unroll
  for (int i = 0; i < 8; ++i) {
    acc[i] += __shfl_xor(acc[i], 16);
    acc[i] += __shfl_xor(acc[i], 32);
  }
  if (lane < 16) {
    const int f0 = lane << 3;
    const float4 b0 = *(const float4*)&bias[f0];
    const float4 b1 = *(const float4*)&bias[f0 + 4];
    float4 o0 = make_float4(0.25f * acc[0] + b0.x, 0.25f * acc[1] + b0.y,
                            0.25f * acc[2] + b0.z, 0.25f * acc[3] + b0.w);
    float4 o1 = make_float4(0.25f * acc[4] + b1.x, 0.25f * acc[5] + b1.y,
                            0.25f * acc[6] + b1.z, 0.25f * acc[7] + b1.w);
    *(float4*)&out[(size_t)n * F_OUT + f0] = o0;
    *(float4*)&out[(size_t)n * F_OUT + f0 + 4] = o1;
  }
}

// ---------------- launch -------------------------------------------------------
extern "C" void kernel_launch(void* const* d_in, const int* in_sizes, int n_in,
                              void* d_out, int out_size, void* d_ws, size_t ws_size,
                              hipStream_t stream) {
  const float* H    = (const float*)d_in[0];
  const int*   ei   = (const int*)d_in[1];
  const float* W    = (const float*)d_in[2];   // [4,128,256] == [512,256]
  const float* a    = (const float*)d_in[3];   // [4,256]
  const float* bias = (const float*)d_in[4];   // [128]
  const int N = in_sizes[0] / F_IN;
  const int E = in_sizes[1] / 2;
  const int* src = ei;
  const int* dst = ei + E;

  char* ws = (char*)d_ws;
  size_t o = 0;
  auto alloc = [&](size_t bytes) -> void* {
    void* p = ws + o;
    o = (o + bytes + 255) & ~(size_t)255;
    return p;
  };
  unsigned short* Hb  = (unsigned short*)alloc((size_t)N * F_IN * sizeof(unsigned short));
  unsigned short* Wb  = (unsigned short*)alloc((size_t)COLS * F_IN * sizeof(unsigned short));
  unsigned short* Ht  = (unsigned short*)alloc((size_t)N * COLS * sizeof(unsigned short)); // 51 MB
  float* ssrc = (float*)alloc((size_t)N * HEADS * sizeof(float));
  float* sdst = (float*)alloc((size_t)N * HEADS * sizeof(float));
  int*   cnt  = (int*)alloc((size_t)N * sizeof(int));
  int*   off  = (int*)alloc(((size_t)N + 1) * sizeof(int));
  int*   cur  = (int*)alloc((size_t)N * sizeof(int));
  int*   csr  = (int*)alloc((size_t)E * sizeof(int));
  const int nb = (N + 1023) / 1024;
  int*   part = (int*)alloc((size_t)N * sizeof(int));
  int*   bsum = (int*)alloc((size_t)nb * sizeof(int));

  hipMemsetAsync(cnt, 0, (size_t)N * sizeof(int), stream);
  hipMemsetAsync(cur, 0, (size_t)N * sizeof(int), stream);

  k_cast<<<2048, 256, 0, stream>>>(H, Hb, N * F_IN / 4);
  k_cast<<<128, 256, 0, stream>>>(W, Wb, COLS * F_IN / 4);

  dim3 ggrid(COLS / 64, (N + 127) / 128);
  k_gemm_bf16<<<ggrid, 256, 0, stream>>>(Hb, Wb, Ht, N);
  k_scores<<<(N + 3) / 4, 256, 0, stream>>>((const uint4*)Ht, a, ssrc, sdst, N);
  k_hist<<<1024, 256, 0, stream>>>(src, cnt, E);
  k_scan1<<<nb, 1024, 0, stream>>>(cnt, part, bsum, N);
  k_scan2<<<1, 64, 0, stream>>>(bsum, nb);
  k_scan3<<<nb, 1024, 0, stream>>>(part, bsum, off, N);
  k_scatter<<<1024, 256, 0, stream>>>(src, dst, off, cur, csr, E);
  k_spmm<<<(N + 3) / 4, 256, 0, stream>>>((const uint4*)Ht, ssrc, sdst, off, csr, bias,
                                          (float*)d_out, N);
}

// Round 4
// 455.905 us; speedup vs baseline: 1.9613x; 1.0340x over previous
//
#include <hip/hip_runtime.h>

#define ALPHA 0.2f
#define EPS 1e-16f

static constexpr int F_IN = 256;
static constexpr int F_OUT = 128;
static constexpr int HEADS = 4;
static constexpr int COLS = HEADS * F_OUT; // 512

typedef __bf16 bf16x8 __attribute__((ext_vector_type(8)));
typedef float f32x4 __attribute__((ext_vector_type(4)));

static __device__ __forceinline__ unsigned short f2bf(float f) {
  unsigned int u = __float_as_uint(f);
  unsigned int r = (u + 0x7FFFu + ((u >> 16) & 1u)) >> 16;  // RN-even
  return (unsigned short)r;
}
static __device__ __forceinline__ float bf_lo(unsigned int u) {
  return __uint_as_float(u << 16);
}
static __device__ __forceinline__ float bf_hi(unsigned int u) {
  return __uint_as_float(u & 0xFFFF0000u);
}

// ---------------- K0: f32 -> bf16 cast (vectorized) ---------------------------
__global__ void k_cast(const float* __restrict__ x, unsigned short* __restrict__ y, int n4) {
  int i = blockIdx.x * blockDim.x + threadIdx.x;
  const int stride = gridDim.x * blockDim.x;
  for (; i < n4; i += stride) {
    const float4 v = ((const float4*)x)[i];
    ((ushort4*)y)[i] = make_ushort4(f2bf(v.x), f2bf(v.y), f2bf(v.z), f2bf(v.w));
  }
}

// ---------------- K1: Ht_bf16[N,512] = Hb[N,256] @ Wb[512,256]^T via MFMA -----
__global__ __launch_bounds__(256) void k_gemm_bf16(const unsigned short* __restrict__ A,
                                                   const unsigned short* __restrict__ B,
                                                   unsigned short* __restrict__ C, int N) {
  // 128(M) x 64(N) tile, BK=32, 4 waves; each wave 32x64 via 2x4 16x16 frags
  __shared__ __bf16 As[128][40];
  __shared__ __bf16 Bs[64][40];
  const int t = threadIdx.x;
  const int w = t >> 6, l = t & 63;
  const int m0 = blockIdx.y << 7, n0 = blockIdx.x << 6;
  const int lr = t >> 2, seg = (t & 3) << 3;
  f32x4 acc[2][4] = {};
  for (int k0 = 0; k0 < F_IN; k0 += 32) {
    int ar0 = m0 + lr;      if (ar0 >= N) ar0 = N - 1;
    int ar1 = m0 + lr + 64; if (ar1 >= N) ar1 = N - 1;
    const uint4 a0 = *(const uint4*)&A[(size_t)ar0 * F_IN + k0 + seg];
    const uint4 a1 = *(const uint4*)&A[(size_t)ar1 * F_IN + k0 + seg];
    const uint4 b0 = *(const uint4*)&B[(size_t)(n0 + lr) * F_IN + k0 + seg];
    __syncthreads();
    *(uint4*)&As[lr][seg] = a0;
    *(uint4*)&As[lr + 64][seg] = a1;
    *(uint4*)&Bs[lr][seg] = b0;
    __syncthreads();
    const int kb = (l >> 4) << 3;
    bf16x8 af[2], bfr[4];
#pragma unroll
    for (int mi = 0; mi < 2; ++mi)
      af[mi] = *(const bf16x8*)&As[(w << 5) + (mi << 4) + (l & 15)][kb];
#pragma unroll
    for (int ni = 0; ni < 4; ++ni)
      bfr[ni] = *(const bf16x8*)&Bs[(ni << 4) + (l & 15)][kb];
#pragma unroll
    for (int mi = 0; mi < 2; ++mi)
#pragma unroll
      for (int ni = 0; ni < 4; ++ni)
        acc[mi][ni] = __builtin_amdgcn_mfma_f32_16x16x32_bf16(af[mi], bfr[ni], acc[mi][ni], 0, 0, 0);
  }
#pragma unroll
  for (int mi = 0; mi < 2; ++mi)
#pragma unroll
    for (int r = 0; r < 4; ++r) {
      const int row = m0 + (w << 5) + (mi << 4) + ((l >> 4) << 2) + r;
      if (row < N) {
#pragma unroll
        for (int ni = 0; ni < 4; ++ni)
          C[(size_t)row * COLS + n0 + (ni << 4) + (l & 15)] = f2bf(acc[mi][ni][r]);
      }
    }
}

// ---------------- K2: per-node scores, vectorized: 4 nodes/block --------------
__global__ __launch_bounds__(256) void k_scores(const uint4* __restrict__ Hb4,
                                                const float* __restrict__ a,
                                                float* __restrict__ ssrc,
                                                float* __restrict__ sdst, int N) {
  const int lane = threadIdx.x & 63;
  const int n = (blockIdx.x << 2) + (threadIdx.x >> 6);
  if (n >= N) return;
  const int hg = lane >> 4;            // head of this lane
  const int f0 = (lane & 15) << 3;     // feature base within head
  const uint4 v = Hb4[(size_t)n * 64 + lane];
  const unsigned int vu[4] = {v.x, v.y, v.z, v.w};
  const float* ah = a + hg * 2 * F_OUT;
  float ss = 0.f, sd = 0.f;
#pragma unroll
  for (int q = 0; q < 4; ++q) {
    const float x0 = bf_lo(vu[q]), x1 = bf_hi(vu[q]);
    ss = fmaf(x0, ah[f0 + 2 * q], fmaf(x1, ah[f0 + 2 * q + 1], ss));
    sd = fmaf(x0, ah[F_OUT + f0 + 2 * q], fmaf(x1, ah[F_OUT + f0 + 2 * q + 1], sd));
  }
#pragma unroll
  for (int m = 1; m < 16; m <<= 1) {
    ss += __shfl_xor(ss, m);
    sd += __shfl_xor(sd, m);
  }
  if ((lane & 15) == 0) {
    ssrc[n * HEADS + hg] = ss;
    sdst[n * HEADS + hg] = sd;
  }
}

// ---------------- CSR build: hist + 3-phase scan + scatter --------------------
__global__ void k_hist(const int* __restrict__ src, int* __restrict__ cnt, int E) {
  int i = blockIdx.x * blockDim.x + threadIdx.x;
  const int stride = gridDim.x * blockDim.x;
  for (; i < E; i += stride) atomicAdd(&cnt[src[i]], 1);
}

__global__ __launch_bounds__(1024) void k_scan1(const int* __restrict__ cnt,
                                                int* __restrict__ part,
                                                int* __restrict__ bsum, int N) {
  __shared__ int ws[16];
  const int t = threadIdx.x, g = blockIdx.x * 1024 + t;
  const int lane = t & 63, w = t >> 6;
  int v = (g < N) ? cnt[g] : 0;
#pragma unroll
  for (int o = 1; o < 64; o <<= 1) {
    const int y = __shfl_up(v, o);
    if (lane >= o) v += y;
  }
  if (lane == 63) ws[w] = v;
  __syncthreads();
  if (w == 0) {
    int s = (lane < 16) ? ws[lane] : 0;
#pragma unroll
    for (int o = 1; o < 16; o <<= 1) {
      const int y = __shfl_up(s, o);
      if (lane >= o) s += y;
    }
    if (lane < 16) ws[lane] = s;
  }
  __syncthreads();
  v += (w > 0) ? ws[w - 1] : 0;
  if (g < N) part[g] = v;                 // inclusive within chunk
  if (t == 1023) bsum[blockIdx.x] = v;
}

__global__ void k_scan2(int* __restrict__ bsum, int nb) {
  const int lane = threadIdx.x;
  int carry = 0;
  for (int base = 0; base < nb; base += 64) {
    int v = (base + lane < nb) ? bsum[base + lane] : 0;
#pragma unroll
    for (int o = 1; o < 64; o <<= 1) {
      const int y = __shfl_up(v, o);
      if (lane >= o) v += y;
    }
    v += carry;
    if (base + lane < nb) bsum[base + lane] = v;  // inclusive
    carry = __shfl(v, 63);
  }
}

__global__ __launch_bounds__(1024) void k_scan3(const int* __restrict__ part,
                                                const int* __restrict__ bsum,
                                                int* __restrict__ off, int N) {
  const int g = blockIdx.x * 1024 + threadIdx.x;
  if (g == 0) off[0] = 0;
  if (g < N) off[g + 1] = part[g] + (blockIdx.x ? bsum[blockIdx.x - 1] : 0);
}

__global__ void k_scatter(const int* __restrict__ src, const int* __restrict__ dst,
                          const int* __restrict__ off, int* __restrict__ cur,
                          int* __restrict__ csr_dst, int E) {
  int i = blockIdx.x * blockDim.x + threadIdx.x;
  const int stride = gridDim.x * blockDim.x;
  for (; i < E; i += stride) {
    const int s = src[i];
    const int p = atomicAdd(&cur[s], 1);
    csr_dst[off[s] + p] = dst[i];
  }
}

// ---------------- K6: fused softmax + SpMM, two-phase batched edges -----------
// Phase A: 64 edges in parallel -> weights & scaled indices parked in LDS.
// Phase B: dependency-free row gathers (many loads in flight per wave).
__global__ __launch_bounds__(256) void k_spmm(const uint4* __restrict__ Hb4,
    const float4* __restrict__ ssrc4, const float4* __restrict__ sdst4,
    const int* __restrict__ off, const int* __restrict__ csr_dst,
    const float* __restrict__ bias, float* __restrict__ out, int N) {
  __shared__ float wbuf[4][4][72];   // [wave][head][edge] pad 72: bcast reads conflict-free
  __shared__ int   ibuf[4][64];
  const int wv = threadIdx.x >> 6;
  const int lane = threadIdx.x & 63;
  const int n = (blockIdx.x << 2) + wv;
  if (n >= N) return;                 // no __syncthreads below: wave-private LDS only
  const int hg = lane >> 4;           // this lane's head
  const float4 ss4 = ssrc4[n];
  float den = 0.f;
  float acc[8] = {};
  const int beg = off[n], end = off[n + 1];
  for (int c0 = beg; c0 < end; c0 += 64) {
    const int cnt = min(64, end - c0);
    if (lane < cnt) {                 // -------- phase A --------
      const int d = csr_dst[c0 + lane];          // coalesced
      ibuf[wv][lane] = d << 6;                   // row base in uint4 units
      const float4 sd4 = sdst4[d];               // 16B gather
      float e0 = ss4.x + sd4.x; e0 = fmaxf(e0, ALPHA * e0);
      float e1 = ss4.y + sd4.y; e1 = fmaxf(e1, ALPHA * e1);
      float e2 = ss4.z + sd4.z; e2 = fmaxf(e2, ALPHA * e2);
      float e3 = ss4.w + sd4.w; e3 = fmaxf(e3, ALPHA * e3);
      wbuf[wv][0][lane] = __expf(e0);
      wbuf[wv][1][lane] = __expf(e1);
      wbuf[wv][2][lane] = __expf(e2);
      wbuf[wv][3][lane] = __expf(e3);
    }
#pragma unroll 4
    for (int j = 0; j < cnt; ++j) {   // -------- phase B --------
      const float wgt = wbuf[wv][hg][j];         // LDS broadcast
      const int db = ibuf[wv][j];                // LDS broadcast
      den += wgt;                                // identical across head group
      const uint4 v = Hb4[db + lane];            // independent 16B gather
      const unsigned int vu[4] = {v.x, v.y, v.z, v.w};
#pragma unroll
      for (int q = 0; q < 4; ++q) {
        acc[2 * q]     = fmaf(wgt, bf_lo(vu[q]), acc[2 * q]);
        acc[2 * q + 1] = fmaf(wgt, bf_hi(vu[q]), acc[2 * q + 1]);
      }
    }
  }
  const float r = 1.f / (den + EPS);
#pragma unroll
  for (int i = 0; i < 8; ++i) acc[i] *= r;
  // combine the 4 heads: lanes l, l^16, l^32, l^48 hold same features
#pragma unroll
  for (int i = 0; i < 8; ++i) {
    acc[i] += __shfl_xor(acc[i], 16);
    acc[i] += __shfl_xor(acc[i], 32);
  }
  if (lane < 16) {
    const int f0 = lane << 3;
    const float4 b0 = *(const float4*)&bias[f0];
    const float4 b1 = *(const float4*)&bias[f0 + 4];
    float4 o0 = make_float4(0.25f * acc[0] + b0.x, 0.25f * acc[1] + b0.y,
                            0.25f * acc[2] + b0.z, 0.25f * acc[3] + b0.w);
    float4 o1 = make_float4(0.25f * acc[4] + b1.x, 0.25f * acc[5] + b1.y,
                            0.25f * acc[6] + b1.z, 0.25f * acc[7] + b1.w);
    *(float4*)&out[(size_t)n * F_OUT + f0] = o0;
    *(float4*)&out[(size_t)n * F_OUT + f0 + 4] = o1;
  }
}

// ---------------- launch -------------------------------------------------------
extern "C" void kernel_launch(void* const* d_in, const int* in_sizes, int n_in,
                              void* d_out, int out_size, void* d_ws, size_t ws_size,
                              hipStream_t stream) {
  const float* H    = (const float*)d_in[0];
  const int*   ei   = (const int*)d_in[1];
  const float* W    = (const float*)d_in[2];   // [4,128,256] == [512,256]
  const float* a    = (const float*)d_in[3];   // [4,256]
  const float* bias = (const float*)d_in[4];   // [128]
  const int N = in_sizes[0] / F_IN;
  const int E = in_sizes[1] / 2;
  const int* src = ei;
  const int* dst = ei + E;

  char* ws = (char*)d_ws;
  size_t o = 0;
  auto alloc = [&](size_t bytes) -> void* {
    void* p = ws + o;
    o = (o + bytes + 255) & ~(size_t)255;
    return p;
  };
  unsigned short* Hb  = (unsigned short*)alloc((size_t)N * F_IN * sizeof(unsigned short));
  unsigned short* Wb  = (unsigned short*)alloc((size_t)COLS * F_IN * sizeof(unsigned short));
  unsigned short* Ht  = (unsigned short*)alloc((size_t)N * COLS * sizeof(unsigned short)); // 51 MB
  float* ssrc = (float*)alloc((size_t)N * HEADS * sizeof(float));
  float* sdst = (float*)alloc((size_t)N * HEADS * sizeof(float));
  int*   cnt  = (int*)alloc((size_t)N * sizeof(int));
  int*   off  = (int*)alloc(((size_t)N + 1) * sizeof(int));
  int*   cur  = (int*)alloc((size_t)N * sizeof(int));
  int*   csr  = (int*)alloc((size_t)E * sizeof(int));
  const int nb = (N + 1023) / 1024;
  int*   part = (int*)alloc((size_t)N * sizeof(int));
  int*   bsum = (int*)alloc((size_t)nb * sizeof(int));

  hipMemsetAsync(cnt, 0, (size_t)N * sizeof(int), stream);
  hipMemsetAsync(cur, 0, (size_t)N * sizeof(int), stream);

  k_cast<<<2048, 256, 0, stream>>>(H, Hb, N * F_IN / 4);
  k_cast<<<128, 256, 0, stream>>>(W, Wb, COLS * F_IN / 4);

  dim3 ggrid(COLS / 64, (N + 127) / 128);
  k_gemm_bf16<<<ggrid, 256, 0, stream>>>(Hb, Wb, Ht, N);
  k_scores<<<(N + 3) / 4, 256, 0, stream>>>((const uint4*)Ht, a, ssrc, sdst, N);
  k_hist<<<1024, 256, 0, stream>>>(src, cnt, E);
  k_scan1<<<nb, 1024, 0, stream>>>(cnt, part, bsum, N);
  k_scan2<<<1, 64, 0, stream>>>(bsum, nb);
  k_scan3<<<nb, 1024, 0, stream>>>(part, bsum, off, N);
  k_scatter<<<1024, 256, 0, stream>>>(src, dst, off, cur, csr, E);
  k_spmm<<<(N + 3) / 4, 256, 0, stream>>>((const uint4*)Ht, (const float4*)ssrc,
                                          (const float4*)sdst, off, csr, bias,
                                          (float*)d_out, N);
}

// Round 5
// 401.042 us; speedup vs baseline: 2.2296x; 1.1368x over previous
//
#include <hip/hip_runtime.h>

#define ALPHA 0.2f
#define EPS 1e-16f

static constexpr int F_IN = 256;
static constexpr int F_OUT = 128;
static constexpr int HEADS = 4;
static constexpr int COLS = HEADS * F_OUT; // 512

typedef __bf16 bf16x8 __attribute__((ext_vector_type(8)));
typedef float f32x4 __attribute__((ext_vector_type(4)));

static __device__ __forceinline__ unsigned short f2bf(float f) {
  unsigned int u = __float_as_uint(f);
  unsigned int r = (u + 0x7FFFu + ((u >> 16) & 1u)) >> 16;  // RN-even
  return (unsigned short)r;
}
static __device__ __forceinline__ float bf_lo(unsigned int u) {
  return __uint_as_float(u << 16);
}
static __device__ __forceinline__ float bf_hi(unsigned int u) {
  return __uint_as_float(u & 0xFFFF0000u);
}

// ---------------- K0: f32 -> bf16 cast (for W only) ---------------------------
__global__ void k_cast(const float* __restrict__ x, unsigned short* __restrict__ y, int n4) {
  int i = blockIdx.x * blockDim.x + threadIdx.x;
  const int stride = gridDim.x * blockDim.x;
  for (; i < n4; i += stride) {
    const float4 v = ((const float4*)x)[i];
    ((ushort4*)y)[i] = make_ushort4(f2bf(v.x), f2bf(v.y), f2bf(v.z), f2bf(v.w));
  }
}

// ---------------- K0b: u[h*2+dual][k] = sum_f a[h][dual*128+f] * W[h][f][k] ---
__global__ void k_uvec(const float* __restrict__ W, const float* __restrict__ a,
                       float* __restrict__ u) {
  const int b = blockIdx.x;        // 0..7 = h*2+dual
  const int h = b >> 1, dual = b & 1;
  const int k = threadIdx.x;       // 0..255
  float s = 0.f;
  for (int f = 0; f < F_OUT; ++f)
    s = fmaf(a[h * 2 * F_OUT + dual * F_OUT + f], W[((size_t)h * F_OUT + f) * F_IN + k], s);
  u[b * F_IN + k] = s;
}

// ---------------- K0c: fused H cast (f32->bf16) + per-node scores (f32) -------
__global__ __launch_bounds__(256) void k_cast_h(const float4* __restrict__ H4,
    const float* __restrict__ u, unsigned short* __restrict__ Hb,
    float4* __restrict__ ssrc4, float4* __restrict__ sdst4, int N) {
  const int wv = threadIdx.x >> 6, lane = threadIdx.x & 63;
  const int n = (blockIdx.x << 2) + wv;
  if (n >= N) return;
  const float4 hv = H4[(size_t)n * 64 + lane];
  *((ushort4*)(Hb + (size_t)n * F_IN) + lane) =
      make_ushort4(f2bf(hv.x), f2bf(hv.y), f2bf(hv.z), f2bf(hv.w));
  float p[8];
#pragma unroll
  for (int c = 0; c < 8; ++c) {
    const float4 uv = *(const float4*)&u[c * F_IN + (lane << 2)];
    p[c] = fmaf(hv.x, uv.x, fmaf(hv.y, uv.y, fmaf(hv.z, uv.z, hv.w * uv.w)));
  }
#pragma unroll
  for (int c = 0; c < 8; ++c)
#pragma unroll
    for (int m = 1; m < 64; m <<= 1) p[c] += __shfl_xor(p[c], m);
  if (lane == 0) {
    ssrc4[n] = make_float4(p[0], p[2], p[4], p[6]);
    sdst4[n] = make_float4(p[1], p[3], p[5], p[7]);
  }
}

// ---------------- K1: Ht_bf16[N,512] = Hb[N,256] @ Wb[512,256]^T via MFMA -----
__global__ __launch_bounds__(256) void k_gemm_bf16(const unsigned short* __restrict__ A,
                                                   const unsigned short* __restrict__ B,
                                                   unsigned short* __restrict__ C, int N) {
  __shared__ __bf16 As[128][40];
  __shared__ __bf16 Bs[64][40];
  const int t = threadIdx.x;
  const int w = t >> 6, l = t & 63;
  const int m0 = blockIdx.y << 7, n0 = blockIdx.x << 6;
  const int lr = t >> 2, seg = (t & 3) << 3;
  f32x4 acc[2][4] = {};
  for (int k0 = 0; k0 < F_IN; k0 += 32) {
    int ar0 = m0 + lr;      if (ar0 >= N) ar0 = N - 1;
    int ar1 = m0 + lr + 64; if (ar1 >= N) ar1 = N - 1;
    const uint4 a0 = *(const uint4*)&A[(size_t)ar0 * F_IN + k0 + seg];
    const uint4 a1 = *(const uint4*)&A[(size_t)ar1 * F_IN + k0 + seg];
    const uint4 b0 = *(const uint4*)&B[(size_t)(n0 + lr) * F_IN + k0 + seg];
    __syncthreads();
    *(uint4*)&As[lr][seg] = a0;
    *(uint4*)&As[lr + 64][seg] = a1;
    *(uint4*)&Bs[lr][seg] = b0;
    __syncthreads();
    const int kb = (l >> 4) << 3;
    bf16x8 af[2], bfr[4];
#pragma unroll
    for (int mi = 0; mi < 2; ++mi)
      af[mi] = *(const bf16x8*)&As[(w << 5) + (mi << 4) + (l & 15)][kb];
#pragma unroll
    for (int ni = 0; ni < 4; ++ni)
      bfr[ni] = *(const bf16x8*)&Bs[(ni << 4) + (l & 15)][kb];
#pragma unroll
    for (int mi = 0; mi < 2; ++mi)
#pragma unroll
      for (int ni = 0; ni < 4; ++ni)
        acc[mi][ni] = __builtin_amdgcn_mfma_f32_16x16x32_bf16(af[mi], bfr[ni], acc[mi][ni], 0, 0, 0);
  }
#pragma unroll
  for (int mi = 0; mi < 2; ++mi)
#pragma unroll
    for (int r = 0; r < 4; ++r) {
      const int row = m0 + (w << 5) + (mi << 4) + ((l >> 4) << 2) + r;
      if (row < N) {
#pragma unroll
        for (int ni = 0; ni < 4; ++ni)
          C[(size_t)row * COLS + n0 + (ni << 4) + (l & 15)] = f2bf(acc[mi][ni][r]);
      }
    }
}

// ---------------- K1b: per-row int8 quantization of Ht ------------------------
__global__ __launch_bounds__(256) void k_quant(const unsigned short* __restrict__ Ht,
                                               uint2* __restrict__ Hq2,
                                               float* __restrict__ scaleArr, int N) {
  const int wv = threadIdx.x >> 6, lane = threadIdx.x & 63;
  const int n = (blockIdx.x << 2) + wv;
  if (n >= N) return;
  const uint4 v = *((const uint4*)(Ht + (size_t)n * COLS) + lane);  // 8 bf16
  const unsigned int vu[4] = {v.x, v.y, v.z, v.w};
  float x[8];
#pragma unroll
  for (int q = 0; q < 4; ++q) { x[2 * q] = bf_lo(vu[q]); x[2 * q + 1] = bf_hi(vu[q]); }
  float mx = 0.f;
#pragma unroll
  for (int k = 0; k < 8; ++k) mx = fmaxf(mx, fabsf(x[k]));
#pragma unroll
  for (int m = 1; m < 64; m <<= 1) mx = fmaxf(mx, __shfl_xor(mx, m));
  const float scl = mx * (1.f / 127.f);
  const float inv = (mx > 0.f) ? 127.f / mx : 0.f;
  int q8[8];
#pragma unroll
  for (int k = 0; k < 8; ++k) {
    float t = rintf(x[k] * inv);
    t = fminf(fmaxf(t, -127.f), 127.f);
    q8[k] = (int)t;
  }
  uint2 pk;
  pk.x = (q8[0] & 255) | ((q8[1] & 255) << 8) | ((q8[2] & 255) << 16) | ((unsigned)(q8[3] & 255) << 24);
  pk.y = (q8[4] & 255) | ((q8[5] & 255) << 8) | ((q8[6] & 255) << 16) | ((unsigned)(q8[7] & 255) << 24);
  Hq2[(size_t)n * 64 + lane] = pk;
  if (lane == 0) scaleArr[n] = scl;
}

// ---------------- CSR build: hist + 3-phase scan + scatter --------------------
__global__ void k_hist(const int* __restrict__ src, int* __restrict__ cnt, int E) {
  int i = blockIdx.x * blockDim.x + threadIdx.x;
  const int stride = gridDim.x * blockDim.x;
  for (; i < E; i += stride) atomicAdd(&cnt[src[i]], 1);
}

__global__ __launch_bounds__(1024) void k_scan1(int* __restrict__ cnt,
                                                int* __restrict__ bsum, int N) {
  __shared__ int ws[16];
  const int t = threadIdx.x, g = blockIdx.x * 1024 + t;
  const int lane = t & 63, w = t >> 6;
  int v = (g < N) ? cnt[g] : 0;
#pragma unroll
  for (int o = 1; o < 64; o <<= 1) {
    const int y = __shfl_up(v, o);
    if (lane >= o) v += y;
  }
  if (lane == 63) ws[w] = v;
  __syncthreads();
  if (w == 0) {
    int s = (lane < 16) ? ws[lane] : 0;
#pragma unroll
    for (int o = 1; o < 16; o <<= 1) {
      const int y = __shfl_up(s, o);
      if (lane >= o) s += y;
    }
    if (lane < 16) ws[lane] = s;
  }
  __syncthreads();
  v += (w > 0) ? ws[w - 1] : 0;
  if (g < N) cnt[g] = v;                  // in-place inclusive within chunk
  if (t == 1023) bsum[blockIdx.x] = v;
}

__global__ void k_scan2(int* __restrict__ bsum, int nb) {
  const int lane = threadIdx.x;
  int carry = 0;
  for (int base = 0; base < nb; base += 64) {
    int v = (base + lane < nb) ? bsum[base + lane] : 0;
#pragma unroll
    for (int o = 1; o < 64; o <<= 1) {
      const int y = __shfl_up(v, o);
      if (lane >= o) v += y;
    }
    v += carry;
    if (base + lane < nb) bsum[base + lane] = v;  // inclusive
    carry = __shfl(v, 63);
  }
}

__global__ __launch_bounds__(1024) void k_scan3(const int* __restrict__ part,
                                                const int* __restrict__ bsum,
                                                int* __restrict__ off, int N) {
  const int g = blockIdx.x * 1024 + threadIdx.x;
  if (g == 0) off[0] = 0;
  if (g < N) off[g + 1] = part[g] + (blockIdx.x ? bsum[blockIdx.x - 1] : 0);
}

__global__ void k_scatter(const int* __restrict__ src, const int* __restrict__ dst,
                          const int* __restrict__ off, int* __restrict__ cur,
                          int* __restrict__ csr_dst, int E) {
  int i = blockIdx.x * blockDim.x + threadIdx.x;
  const int stride = gridDim.x * blockDim.x;
  for (; i < E; i += stride) {
    const int s = src[i];
    const int p = atomicAdd(&cur[s], 1);
    csr_dst[off[s] + p] = dst[i];
  }
}

// ---------------- K6: fused softmax + SpMM, int8 rows + two-phase batching ----
__global__ __launch_bounds__(256) void k_spmm(const uint2* __restrict__ Hq2,
    const float4* __restrict__ ssrc4, const float4* __restrict__ sdst4,
    const float* __restrict__ scaleArr,
    const int* __restrict__ off, const int* __restrict__ csr_dst,
    const float* __restrict__ bias, float* __restrict__ out, int N) {
  __shared__ float wbuf[4][4][72];   // [wave][head][edge], scaled weights
  __shared__ int   ibuf[4][64];
  const int wv = threadIdx.x >> 6;
  const int lane = threadIdx.x & 63;
  const int n = (blockIdx.x << 2) + wv;
  if (n >= N) return;                 // wave-private LDS, no barriers
  const int hg = lane >> 4;
  const float4 ss4 = ssrc4[n];
  float den4[4] = {};
  float acc[8] = {};
  const int beg = off[n], end = off[n + 1];
  for (int c0 = beg; c0 < end; c0 += 64) {
    const int cnt = min(64, end - c0);
    if (lane < cnt) {                 // -------- phase A --------
      const int d = csr_dst[c0 + lane];          // coalesced
      ibuf[wv][lane] = d << 6;                   // row base in uint2 units
      const float scl = scaleArr[d];             // 4B gather
      const float4 sd4 = sdst4[d];               // 16B gather
      float e0 = ss4.x + sd4.x; e0 = fmaxf(e0, ALPHA * e0);
      float e1 = ss4.y + sd4.y; e1 = fmaxf(e1, ALPHA * e1);
      float e2 = ss4.z + sd4.z; e2 = fmaxf(e2, ALPHA * e2);
      float e3 = ss4.w + sd4.w; e3 = fmaxf(e3, ALPHA * e3);
      const float w0 = __expf(e0), w1 = __expf(e1), w2 = __expf(e2), w3 = __expf(e3);
      den4[0] += w0; den4[1] += w1; den4[2] += w2; den4[3] += w3;
      wbuf[wv][0][lane] = w0 * scl;
      wbuf[wv][1][lane] = w1 * scl;
      wbuf[wv][2][lane] = w2 * scl;
      wbuf[wv][3][lane] = w3 * scl;
    }
#pragma unroll 8
    for (int j = 0; j < cnt; ++j) {   // -------- phase B --------
      const float wgt = wbuf[wv][hg][j];         // LDS broadcast (scaled)
      const int db = ibuf[wv][j];                // LDS broadcast
      const uint2 q = Hq2[db + lane];            // 8B gather, 512B/row/wave
      acc[0] = fmaf(wgt, (float)(char)(q.x),       acc[0]);
      acc[1] = fmaf(wgt, (float)(char)(q.x >> 8),  acc[1]);
      acc[2] = fmaf(wgt, (float)(char)(q.x >> 16), acc[2]);
      acc[3] = fmaf(wgt, (float)(char)(q.x >> 24), acc[3]);
      acc[4] = fmaf(wgt, (float)(char)(q.y),       acc[4]);
      acc[5] = fmaf(wgt, (float)(char)(q.y >> 8),  acc[5]);
      acc[6] = fmaf(wgt, (float)(char)(q.y >> 16), acc[6]);
      acc[7] = fmaf(wgt, (float)(char)(q.y >> 24), acc[7]);
    }
  }
  // reduce raw denominators across the wave (lanes hold disjoint edge partials)
#pragma unroll
  for (int k = 0; k < 4; ++k)
#pragma unroll
    for (int m = 1; m < 64; m <<= 1) den4[k] += __shfl_xor(den4[k], m);
  const float r = 1.f / (den4[hg] + EPS);
#pragma unroll
  for (int i = 0; i < 8; ++i) acc[i] *= r;
#pragma unroll
  for (int i = 0; i < 8; ++i) {
    acc[i] += __shfl_xor(acc[i], 16);
    acc[i] += __shfl_xor(acc[i], 32);
  }
  if (lane < 16) {
    const int f0 = lane << 3;
    const float4 b0 = *(const float4*)&bias[f0];
    const float4 b1 = *(const float4*)&bias[f0 + 4];
    float4 o0 = make_float4(0.25f * acc[0] + b0.x, 0.25f * acc[1] + b0.y,
                            0.25f * acc[2] + b0.z, 0.25f * acc[3] + b0.w);
    float4 o1 = make_float4(0.25f * acc[4] + b1.x, 0.25f * acc[5] + b1.y,
                            0.25f * acc[6] + b1.z, 0.25f * acc[7] + b1.w);
    *(float4*)&out[(size_t)n * F_OUT + f0] = o0;
    *(float4*)&out[(size_t)n * F_OUT + f0 + 4] = o1;
  }
}

// ---------------- launch -------------------------------------------------------
extern "C" void kernel_launch(void* const* d_in, const int* in_sizes, int n_in,
                              void* d_out, int out_size, void* d_ws, size_t ws_size,
                              hipStream_t stream) {
  const float* H    = (const float*)d_in[0];
  const int*   ei   = (const int*)d_in[1];
  const float* W    = (const float*)d_in[2];   // [4,128,256] == [512,256]
  const float* a    = (const float*)d_in[3];   // [4,256]
  const float* bias = (const float*)d_in[4];   // [128]
  const int N = in_sizes[0] / F_IN;
  const int E = in_sizes[1] / 2;
  const int* src = ei;
  const int* dst = ei + E;

  char* ws = (char*)d_ws;
  size_t o = 0;
  auto alloc = [&](size_t bytes) -> void* {
    void* p = ws + o;
    o = (o + bytes + 255) & ~(size_t)255;
    return p;
  };
  unsigned short* Hb  = (unsigned short*)alloc((size_t)N * F_IN * 2);   // 25.6 MB (reused as Hq)
  unsigned short* Wb  = (unsigned short*)alloc((size_t)COLS * F_IN * 2);
  unsigned short* Ht  = (unsigned short*)alloc((size_t)N * COLS * 2);   // 51 MB
  float* uvec = (float*)alloc(8 * F_IN * sizeof(float));
  float* ssrc = (float*)alloc((size_t)N * HEADS * sizeof(float));
  float* sdst = (float*)alloc((size_t)N * HEADS * sizeof(float));
  float* scal = (float*)alloc((size_t)N * sizeof(float));
  int*   cnt  = (int*)alloc((size_t)N * sizeof(int));   // becomes inclusive-scan "part"
  int*   off  = (int*)alloc(((size_t)N + 1) * sizeof(int));
  int*   cur  = (int*)alloc((size_t)N * sizeof(int));
  int*   csr  = (int*)alloc((size_t)E * sizeof(int));
  const int nb = (N + 1023) / 1024;
  int*   bsum = (int*)alloc((size_t)nb * sizeof(int));
  uint2* Hq2  = (uint2*)Hb;   // alias: Hb dead after gemm, Hq written after

  hipMemsetAsync(cnt, 0, (size_t)N * sizeof(int), stream);
  hipMemsetAsync(cur, 0, (size_t)N * sizeof(int), stream);

  k_cast<<<128, 256, 0, stream>>>(W, Wb, COLS * F_IN / 4);
  k_uvec<<<8, 256, 0, stream>>>(W, a, uvec);
  k_cast_h<<<(N + 3) / 4, 256, 0, stream>>>((const float4*)H, uvec, Hb,
                                            (float4*)ssrc, (float4*)sdst, N);
  dim3 ggrid(COLS / 64, (N + 127) / 128);
  k_gemm_bf16<<<ggrid, 256, 0, stream>>>(Hb, Wb, Ht, N);
  k_quant<<<(N + 3) / 4, 256, 0, stream>>>(Ht, Hq2, scal, N);
  k_hist<<<1024, 256, 0, stream>>>(src, cnt, E);
  k_scan1<<<nb, 1024, 0, stream>>>(cnt, bsum, N);
  k_scan2<<<1, 64, 0, stream>>>(bsum, nb);
  k_scan3<<<nb, 1024, 0, stream>>>(cnt, bsum, off, N);
  k_scatter<<<1024, 256, 0, stream>>>(src, dst, off, cur, csr, E);
  k_spmm<<<(N + 3) / 4, 256, 0, stream>>>(Hq2, (const float4*)ssrc, (const float4*)sdst,
                                          scal, off, csr, bias, (float*)d_out, N);
}

// Round 6
// 317.531 us; speedup vs baseline: 2.8160x; 1.2630x over previous
//
#include <hip/hip_runtime.h>

#define ALPHA 0.2f
#define EPS 1e-16f

static constexpr int F_IN = 256;
static constexpr int F_OUT = 128;
static constexpr int HEADS = 4;
static constexpr int COLS = HEADS * F_OUT; // 512

typedef __bf16 bf16x8 __attribute__((ext_vector_type(8)));
typedef float f32x4 __attribute__((ext_vector_type(4)));

static __device__ __forceinline__ unsigned short f2bf(float f) {
  unsigned int u = __float_as_uint(f);
  unsigned int r = (u + 0x7FFFu + ((u >> 16) & 1u)) >> 16;  // RN-even
  return (unsigned short)r;
}

// ---------------- K0: W cast to bf16 (blocks 0..127) + uvec (blocks 128..135) --
__global__ __launch_bounds__(256) void k_wprep(const float* __restrict__ W,
                                               const float* __restrict__ a,
                                               unsigned short* __restrict__ Wb,
                                               float* __restrict__ u) {
  if (blockIdx.x < 128) {
    const int i = blockIdx.x * 256 + threadIdx.x;   // n4 = 512*256/4 = 32768
    const float4 v = ((const float4*)W)[i];
    ((ushort4*)Wb)[i] = make_ushort4(f2bf(v.x), f2bf(v.y), f2bf(v.z), f2bf(v.w));
  } else {
    const int b = blockIdx.x - 128;  // 0..7 = h*2+dual
    const int h = b >> 1, dual = b & 1;
    const int k = threadIdx.x;
    float s = 0.f;
    for (int f = 0; f < F_OUT; ++f)
      s = fmaf(a[h * 2 * F_OUT + dual * F_OUT + f], W[((size_t)h * F_OUT + f) * F_IN + k], s);
    u[b * F_IN + k] = s;
  }
}

// ---------------- K1: fused H cast + scores (blocks < CB) + edge rank (rest) --
__global__ __launch_bounds__(256) void k_pre(const float4* __restrict__ H4,
    const float* __restrict__ u, unsigned short* __restrict__ Hb,
    float4* __restrict__ ssrc4, float4* __restrict__ sdst4, int N, int CB,
    const int* __restrict__ src, int* __restrict__ cnt,
    unsigned short* __restrict__ rank, int E) {
  if ((int)blockIdx.x >= CB) {  // ---- edge rank pass (1024 blocks) ----
    int i = (blockIdx.x - CB) * 256 + threadIdx.x;
    const int stride = 1024 * 256;
    for (; i < E; i += stride) rank[i] = (unsigned short)atomicAdd(&cnt[src[i]], 1);
    return;
  }
  const int wv = threadIdx.x >> 6, lane = threadIdx.x & 63;
  const int n = ((int)blockIdx.x << 2) + wv;
  if (n >= N) return;
  const float4 hv = H4[(size_t)n * 64 + lane];
  *((ushort4*)(Hb + (size_t)n * F_IN) + lane) =
      make_ushort4(f2bf(hv.x), f2bf(hv.y), f2bf(hv.z), f2bf(hv.w));
  float p[8];
#pragma unroll
  for (int c = 0; c < 8; ++c) {
    const float4 uv = *(const float4*)&u[c * F_IN + (lane << 2)];
    p[c] = fmaf(hv.x, uv.x, fmaf(hv.y, uv.y, fmaf(hv.z, uv.z, hv.w * uv.w)));
  }
#pragma unroll
  for (int c = 0; c < 8; ++c)
#pragma unroll
    for (int m = 1; m < 64; m <<= 1) p[c] += __shfl_xor(p[c], m);
  if (lane == 0) {
    ssrc4[n] = make_float4(p[0], p[2], p[4], p[6]);
    sdst4[n] = make_float4(p[1], p[3], p[5], p[7]);
  }
}

// ---------------- K2: MFMA GEMM with fused int8 quant epilogue ----------------
// Hq row layout (per 64-col block b): u32 at byte 64b+4k holds cols {0,16,32,48}+k.
__global__ __launch_bounds__(256) void k_gemm_q(const unsigned short* __restrict__ A,
                                                const unsigned short* __restrict__ B,
                                                unsigned char* __restrict__ Hq,
                                                float* __restrict__ scl8, int N) {
  __shared__ __bf16 As[128][40];
  __shared__ __bf16 Bs[64][40];
  const int t = threadIdx.x;
  const int w = t >> 6, l = t & 63;
  const int bx = blockIdx.x;               // n-block 0..7
  const int m0 = blockIdx.y << 7, n0 = bx << 6;
  const int lr = t >> 2, seg = (t & 3) << 3;
  f32x4 acc[2][4] = {};
  for (int k0 = 0; k0 < F_IN; k0 += 32) {
    int ar0 = m0 + lr;      if (ar0 >= N) ar0 = N - 1;
    int ar1 = m0 + lr + 64; if (ar1 >= N) ar1 = N - 1;
    const uint4 a0 = *(const uint4*)&A[(size_t)ar0 * F_IN + k0 + seg];
    const uint4 a1 = *(const uint4*)&A[(size_t)ar1 * F_IN + k0 + seg];
    const uint4 b0 = *(const uint4*)&B[(size_t)(n0 + lr) * F_IN + k0 + seg];
    __syncthreads();
    *(uint4*)&As[lr][seg] = a0;
    *(uint4*)&As[lr + 64][seg] = a1;
    *(uint4*)&Bs[lr][seg] = b0;
    __syncthreads();
    const int kb = (l >> 4) << 3;
    bf16x8 af[2], bfr[4];
#pragma unroll
    for (int mi = 0; mi < 2; ++mi)
      af[mi] = *(const bf16x8*)&As[(w << 5) + (mi << 4) + (l & 15)][kb];
#pragma unroll
    for (int ni = 0; ni < 4; ++ni)
      bfr[ni] = *(const bf16x8*)&Bs[(ni << 4) + (l & 15)][kb];
#pragma unroll
    for (int mi = 0; mi < 2; ++mi)
#pragma unroll
      for (int ni = 0; ni < 4; ++ni)
        acc[mi][ni] = __builtin_amdgcn_mfma_f32_16x16x32_bf16(af[mi], bfr[ni], acc[mi][ni], 0, 0, 0);
  }
  // quant epilogue: per-row absmax over this 64-col block, int8 pack, permuted store
#pragma unroll
  for (int mi = 0; mi < 2; ++mi)
#pragma unroll
    for (int r = 0; r < 4; ++r) {
      float mx = 0.f;
#pragma unroll
      for (int ni = 0; ni < 4; ++ni) mx = fmaxf(mx, fabsf(acc[mi][ni][r]));
#pragma unroll
      for (int m = 1; m < 16; m <<= 1) mx = fmaxf(mx, __shfl_xor(mx, m));
      const int row = m0 + (w << 5) + (mi << 4) + ((l >> 4) << 2) + r;
      if (row < N) {
        const float inv = (mx > 0.f) ? 127.f / mx : 0.f;
        if ((l & 15) == 0) scl8[row * 8 + bx] = mx * (1.f / 127.f);
        unsigned int pk = 0;
#pragma unroll
        for (int ni = 0; ni < 4; ++ni) {
          float tq = fminf(fmaxf(rintf(acc[mi][ni][r] * inv), -127.f), 127.f);
          pk |= ((unsigned int)((int)tq & 255)) << (8 * ni);
        }
        *(unsigned int*)&Hq[(size_t)row * 512 + (bx << 6) + ((l & 15) << 2)] = pk;
      }
    }
}

// ---------------- scans over cnt -> off ---------------------------------------
__global__ __launch_bounds__(1024) void k_scan1(int* __restrict__ cnt,
                                                int* __restrict__ bsum, int N) {
  __shared__ int ws[16];
  const int t = threadIdx.x, g = blockIdx.x * 1024 + t;
  const int lane = t & 63, w = t >> 6;
  int v = (g < N) ? cnt[g] : 0;
#pragma unroll
  for (int o = 1; o < 64; o <<= 1) {
    const int y = __shfl_up(v, o);
    if (lane >= o) v += y;
  }
  if (lane == 63) ws[w] = v;
  __syncthreads();
  if (w == 0) {
    int s = (lane < 16) ? ws[lane] : 0;
#pragma unroll
    for (int o = 1; o < 16; o <<= 1) {
      const int y = __shfl_up(s, o);
      if (lane >= o) s += y;
    }
    if (lane < 16) ws[lane] = s;
  }
  __syncthreads();
  v += (w > 0) ? ws[w - 1] : 0;
  if (g < N) cnt[g] = v;                  // in-place inclusive within chunk
  if (t == 1023) bsum[blockIdx.x] = v;
}

__global__ void k_scan2(int* __restrict__ bsum, int nb) {
  const int lane = threadIdx.x;
  int carry = 0;
  for (int base = 0; base < nb; base += 64) {
    int v = (base + lane < nb) ? bsum[base + lane] : 0;
#pragma unroll
    for (int o = 1; o < 64; o <<= 1) {
      const int y = __shfl_up(v, o);
      if (lane >= o) v += y;
    }
    v += carry;
    if (base + lane < nb) bsum[base + lane] = v;
    carry = __shfl(v, 63);
  }
}

__global__ __launch_bounds__(1024) void k_scan3(const int* __restrict__ part,
                                                const int* __restrict__ bsum,
                                                int* __restrict__ off, int N) {
  const int g = blockIdx.x * 1024 + threadIdx.x;
  if (g == 0) off[0] = 0;
  if (g < N) off[g + 1] = part[g] + (blockIdx.x ? bsum[blockIdx.x - 1] : 0);
}

// ---------------- K3: scatter (no atomics: rank precomputed) ------------------
__global__ void k_scatter(const int* __restrict__ src, const int* __restrict__ dst,
                          const int* __restrict__ off, const unsigned short* __restrict__ rank,
                          int* __restrict__ csr_dst, int E) {
  int i = blockIdx.x * blockDim.x + threadIdx.x;
  const int stride = gridDim.x * blockDim.x;
  for (; i < E; i += stride) csr_dst[off[src[i]] + rank[i]] = dst[i];
}

// ---------------- K4: fused softmax + SpMM, int8 + per-block scales -----------
__global__ __launch_bounds__(256) void k_spmm(const uint2* __restrict__ Hq2,
    const float4* __restrict__ ssrc4, const float4* __restrict__ sdst4,
    const float4* __restrict__ scl8_4,
    const int* __restrict__ off, const int* __restrict__ csr_dst,
    const float* __restrict__ bias, float* __restrict__ out, int N) {
  __shared__ float wbuf[4][8][72];   // [wave][col-block][edge], w[h]*scl8[d][b]
  __shared__ int   ibuf[4][64];
  const int wv = threadIdx.x >> 6;
  const int lane = threadIdx.x & 63;
  const int n = (blockIdx.x << 2) + wv;
  if (n >= N) return;                 // wave-private LDS, no barriers
  const int hg = lane >> 4;           // head of this lane
  const int b8 = lane >> 3;           // 64-col block of this lane
  const float4 ss4 = ssrc4[n];
  float den4[4] = {};
  float acc[8] = {};
  const int beg = off[n], end = off[n + 1];
  for (int c0 = beg; c0 < end; c0 += 64) {
    const int cnt = min(64, end - c0);
    if (lane < cnt) {                 // -------- phase A --------
      const int d = csr_dst[c0 + lane];          // coalesced
      ibuf[wv][lane] = d << 6;                   // row base in uint2 units
      const float4 sA = scl8_4[d * 2];
      const float4 sB = scl8_4[d * 2 + 1];
      const float4 sd4 = sdst4[d];
      float e0 = ss4.x + sd4.x; e0 = fmaxf(e0, ALPHA * e0);
      float e1 = ss4.y + sd4.y; e1 = fmaxf(e1, ALPHA * e1);
      float e2 = ss4.z + sd4.z; e2 = fmaxf(e2, ALPHA * e2);
      float e3 = ss4.w + sd4.w; e3 = fmaxf(e3, ALPHA * e3);
      const float w0 = __expf(e0), w1 = __expf(e1), w2 = __expf(e2), w3 = __expf(e3);
      den4[0] += w0; den4[1] += w1; den4[2] += w2; den4[3] += w3;
      wbuf[wv][0][lane] = w0 * sA.x; wbuf[wv][1][lane] = w0 * sA.y;
      wbuf[wv][2][lane] = w1 * sA.z; wbuf[wv][3][lane] = w1 * sA.w;
      wbuf[wv][4][lane] = w2 * sB.x; wbuf[wv][5][lane] = w2 * sB.y;
      wbuf[wv][6][lane] = w3 * sB.z; wbuf[wv][7][lane] = w3 * sB.w;
    }
#pragma unroll 8
    for (int j = 0; j < cnt; ++j) {   // -------- phase B --------
      const float wgt = wbuf[wv][b8][j];         // LDS broadcast (scaled)
      const int db = ibuf[wv][j];                // LDS broadcast
      const uint2 q = Hq2[db + lane];            // 8B gather, 512B/row/wave
      acc[0] = fmaf(wgt, (float)(char)(q.x),       acc[0]);
      acc[1] = fmaf(wgt, (float)(char)(q.x >> 8),  acc[1]);
      acc[2] = fmaf(wgt, (float)(char)(q.x >> 16), acc[2]);
      acc[3] = fmaf(wgt, (float)(char)(q.x >> 24), acc[3]);
      acc[4] = fmaf(wgt, (float)(char)(q.y),       acc[4]);
      acc[5] = fmaf(wgt, (float)(char)(q.y >> 8),  acc[5]);
      acc[6] = fmaf(wgt, (float)(char)(q.y >> 16), acc[6]);
      acc[7] = fmaf(wgt, (float)(char)(q.y >> 24), acc[7]);
    }
  }
#pragma unroll
  for (int k = 0; k < 4; ++k)
#pragma unroll
    for (int m = 1; m < 64; m <<= 1) den4[k] += __shfl_xor(den4[k], m);
  const float r = 1.f / (den4[hg] + EPS);
#pragma unroll
  for (int i = 0; i < 8; ++i) acc[i] *= r;
#pragma unroll
  for (int i = 0; i < 8; ++i) {       // sum the 4 heads (same feature at l^16,l^32)
    acc[i] += __shfl_xor(acc[i], 16);
    acc[i] += __shfl_xor(acc[i], 32);
  }
  if (lane < 16) {
    // permuted layout: acc[i] = feature 64*((lane>>3)&1) + (i&3)*16 + 2*(lane&7) + (i>>2)
    const int base = ((lane >> 3) & 1) * 64 + ((lane & 7) << 1);
#pragma unroll
    for (int k = 0; k < 4; ++k) {
      const float2 b2 = *(const float2*)&bias[base + k * 16];
      *(float2*)&out[(size_t)n * F_OUT + base + k * 16] =
          make_float2(0.25f * acc[k] + b2.x, 0.25f * acc[k + 4] + b2.y);
    }
  }
}

// ---------------- launch -------------------------------------------------------
extern "C" void kernel_launch(void* const* d_in, const int* in_sizes, int n_in,
                              void* d_out, int out_size, void* d_ws, size_t ws_size,
                              hipStream_t stream) {
  const float* H    = (const float*)d_in[0];
  const int*   ei   = (const int*)d_in[1];
  const float* W    = (const float*)d_in[2];   // [4,128,256] == [512,256]
  const float* a    = (const float*)d_in[3];   // [4,256]
  const float* bias = (const float*)d_in[4];   // [128]
  const int N = in_sizes[0] / F_IN;
  const int E = in_sizes[1] / 2;
  const int* src = ei;
  const int* dst = ei + E;

  char* ws = (char*)d_ws;
  size_t o = 0;
  auto alloc = [&](size_t bytes) -> void* {
    void* p = ws + o;
    o = (o + bytes + 255) & ~(size_t)255;
    return p;
  };
  unsigned short* Hb  = (unsigned short*)alloc((size_t)N * F_IN * 2);   // 25.6 MB bf16 H
  unsigned short* Wb  = (unsigned short*)alloc((size_t)COLS * F_IN * 2);
  unsigned char*  Hq  = (unsigned char*)alloc((size_t)N * COLS);        // 25.6 MB int8
  float* uvec = (float*)alloc(8 * F_IN * sizeof(float));
  float* ssrc = (float*)alloc((size_t)N * HEADS * sizeof(float));
  float* sdst = (float*)alloc((size_t)N * HEADS * sizeof(float));
  float* scl8 = (float*)alloc((size_t)N * 8 * sizeof(float));           // 1.6 MB
  int*   cnt  = (int*)alloc((size_t)N * sizeof(int));
  int*   off  = (int*)alloc(((size_t)N + 1) * sizeof(int));
  int*   csr  = (int*)alloc((size_t)E * sizeof(int));
  unsigned short* rank = (unsigned short*)alloc((size_t)E * sizeof(unsigned short));
  const int nb = (N + 1023) / 1024;
  int*   bsum = (int*)alloc((size_t)nb * sizeof(int));

  hipMemsetAsync(cnt, 0, (size_t)N * sizeof(int), stream);

  k_wprep<<<136, 256, 0, stream>>>(W, a, Wb, uvec);
  const int CB = (N + 3) / 4;
  k_pre<<<CB + 1024, 256, 0, stream>>>((const float4*)H, uvec, Hb,
                                       (float4*)ssrc, (float4*)sdst, N, CB,
                                       src, cnt, rank, E);
  dim3 ggrid(COLS / 64, (N + 127) / 128);
  k_gemm_q<<<ggrid, 256, 0, stream>>>(Hb, Wb, Hq, scl8, N);
  k_scan1<<<nb, 1024, 0, stream>>>(cnt, bsum, N);
  k_scan2<<<1, 64, 0, stream>>>(bsum, nb);
  k_scan3<<<nb, 1024, 0, stream>>>(cnt, bsum, off, N);
  k_scatter<<<1024, 256, 0, stream>>>(src, dst, off, rank, csr, E);
  k_spmm<<<(N + 3) / 4, 256, 0, stream>>>((const uint2*)Hq, (const float4*)ssrc,
                                          (const float4*)sdst, (const float4*)scl8,
                                          off, csr, bias, (float*)d_out, N);
}

// Round 7
// 300.835 us; speedup vs baseline: 2.9723x; 1.0555x over previous
//
#include <hip/hip_runtime.h>

#define ALPHA 0.2f
#define EPS 1e-16f

static constexpr int F_IN = 256;
static constexpr int F_OUT = 128;
static constexpr int HEADS = 4;
static constexpr int COLS = HEADS * F_OUT; // 512

typedef __bf16 bf16x8 __attribute__((ext_vector_type(8)));
typedef float f32x4 __attribute__((ext_vector_type(4)));

static __device__ __forceinline__ unsigned short f2bf(float f) {
  unsigned int u = __float_as_uint(f);
  unsigned int r = (u + 0x7FFFu + ((u >> 16) & 1u)) >> 16;  // RN-even
  return (unsigned short)r;
}
static __device__ __forceinline__ float bf_lo(unsigned int u) {
  return __uint_as_float(u << 16);
}
static __device__ __forceinline__ float bf_hi(unsigned int u) {
  return __uint_as_float(u & 0xFFFF0000u);
}

// ---------------- K0: W cast to bf16 (blocks 0..127) + uvec (blocks 128..135) --
__global__ __launch_bounds__(256) void k_wprep(const float* __restrict__ W,
                                               const float* __restrict__ a,
                                               unsigned short* __restrict__ Wb,
                                               float* __restrict__ u) {
  if (blockIdx.x < 128) {
    const int i = blockIdx.x * 256 + threadIdx.x;   // n4 = 512*256/4 = 32768
    const float4 v = ((const float4*)W)[i];
    ((ushort4*)Wb)[i] = make_ushort4(f2bf(v.x), f2bf(v.y), f2bf(v.z), f2bf(v.w));
  } else {
    const int b = blockIdx.x - 128;  // 0..7 = h*2+dual
    const int h = b >> 1, dual = b & 1;
    const int k = threadIdx.x;
    float s = 0.f;
    for (int f = 0; f < F_OUT; ++f)
      s = fmaf(a[h * 2 * F_OUT + dual * F_OUT + f], W[((size_t)h * F_OUT + f) * F_IN + k], s);
    u[b * F_IN + k] = s;
  }
}

// ---------------- K1: fused H cast + scores (blocks < CB) + edge rank (rest) --
// rec[n] (32B): bytes 0..15 = sdst (4 f32); bytes 16..31 = 8 bf16 scales (by gemm)
__global__ __launch_bounds__(256) void k_pre(const float4* __restrict__ H4,
    const float* __restrict__ u, unsigned short* __restrict__ Hb,
    float4* __restrict__ ssrc4, unsigned char* __restrict__ rec, int N, int CB,
    const int* __restrict__ src, int* __restrict__ cnt,
    unsigned short* __restrict__ rank, int E) {
  if ((int)blockIdx.x >= CB) {  // ---- edge rank pass (1024 blocks) ----
    int i = (blockIdx.x - CB) * 256 + threadIdx.x;
    const int stride = 1024 * 256;
    for (; i < E; i += stride) rank[i] = (unsigned short)atomicAdd(&cnt[src[i]], 1);
    return;
  }
  const int wv = threadIdx.x >> 6, lane = threadIdx.x & 63;
  const int n = ((int)blockIdx.x << 2) + wv;
  if (n >= N) return;
  const float4 hv = H4[(size_t)n * 64 + lane];
  *((ushort4*)(Hb + (size_t)n * F_IN) + lane) =
      make_ushort4(f2bf(hv.x), f2bf(hv.y), f2bf(hv.z), f2bf(hv.w));
  float p[8];
#pragma unroll
  for (int c = 0; c < 8; ++c) {
    const float4 uv = *(const float4*)&u[c * F_IN + (lane << 2)];
    p[c] = fmaf(hv.x, uv.x, fmaf(hv.y, uv.y, fmaf(hv.z, uv.z, hv.w * uv.w)));
  }
#pragma unroll
  for (int c = 0; c < 8; ++c)
#pragma unroll
    for (int m = 1; m < 64; m <<= 1) p[c] += __shfl_xor(p[c], m);
  if (lane == 0) {
    ssrc4[n] = make_float4(p[0], p[2], p[4], p[6]);
    *(float4*)&rec[(size_t)n * 32] = make_float4(p[1], p[3], p[5], p[7]);
  }
}

// ---------------- K2: 128x128 MFMA GEMM with fused int8 quant epilogue --------
// Hq row layout (per 64-col block b): u32 at byte 64b+4k holds cols {0,16,32,48}+k.
__global__ __launch_bounds__(256) void k_gemm_q(const unsigned short* __restrict__ A,
                                                const unsigned short* __restrict__ B,
                                                unsigned char* __restrict__ Hq,
                                                unsigned char* __restrict__ rec, int N) {
  __shared__ __bf16 As[128][40];
  __shared__ __bf16 Bs[128][40];
  const int t = threadIdx.x;
  const int w = t >> 6, l = t & 63;
  const int wr = w >> 1, wc = w & 1;       // 2x2 wave grid, each 64x64
  const int m0 = blockIdx.y << 7, n0 = blockIdx.x << 7;
  const int lr = t >> 1, seg16 = (t & 1) << 4;   // staging: row 0..127, col 0/16
  f32x4 acc[4][4] = {};
  for (int k0 = 0; k0 < F_IN; k0 += 32) {
    int ar = m0 + lr; if (ar >= N) ar = N - 1;   // clamp; stores guarded
    const uint4 a0 = *(const uint4*)&A[(size_t)ar * F_IN + k0 + seg16];
    const uint4 a1 = *(const uint4*)&A[(size_t)ar * F_IN + k0 + seg16 + 8];
    const uint4 b0 = *(const uint4*)&B[(size_t)(n0 + lr) * F_IN + k0 + seg16];
    const uint4 b1 = *(const uint4*)&B[(size_t)(n0 + lr) * F_IN + k0 + seg16 + 8];
    __syncthreads();
    *(uint4*)&As[lr][seg16] = a0;  *(uint4*)&As[lr][seg16 + 8] = a1;
    *(uint4*)&Bs[lr][seg16] = b0;  *(uint4*)&Bs[lr][seg16 + 8] = b1;
    __syncthreads();
    const int kb = (l >> 4) << 3;
    bf16x8 af[4], bf_[4];
#pragma unroll
    for (int mi = 0; mi < 4; ++mi)
      af[mi] = *(const bf16x8*)&As[(wr << 6) + (mi << 4) + (l & 15)][kb];
#pragma unroll
    for (int ni = 0; ni < 4; ++ni)
      bf_[ni] = *(const bf16x8*)&Bs[(wc << 6) + (ni << 4) + (l & 15)][kb];
#pragma unroll
    for (int mi = 0; mi < 4; ++mi)
#pragma unroll
      for (int ni = 0; ni < 4; ++ni)
        acc[mi][ni] = __builtin_amdgcn_mfma_f32_16x16x32_bf16(af[mi], bf_[ni], acc[mi][ni], 0, 0, 0);
  }
  const int bxg = (blockIdx.x << 1) + wc;  // global 64-col block 0..7
#pragma unroll
  for (int mi = 0; mi < 4; ++mi)
#pragma unroll
    for (int r = 0; r < 4; ++r) {
      float mx = 0.f;
#pragma unroll
      for (int ni = 0; ni < 4; ++ni) mx = fmaxf(mx, fabsf(acc[mi][ni][r]));
#pragma unroll
      for (int m = 1; m < 16; m <<= 1) mx = fmaxf(mx, __shfl_xor(mx, m));
      const int row = m0 + (wr << 6) + (mi << 4) + ((l >> 4) << 2) + r;
      if (row < N) {
        const float inv = (mx > 0.f) ? 127.f / mx : 0.f;
        if ((l & 15) == 0)
          *(unsigned short*)&rec[(size_t)row * 32 + 16 + (bxg << 1)] = f2bf(mx * (1.f / 127.f));
        unsigned int pk = 0;
#pragma unroll
        for (int ni = 0; ni < 4; ++ni) {
          float tq = fminf(fmaxf(rintf(acc[mi][ni][r] * inv), -127.f), 127.f);
          pk |= ((unsigned int)((int)tq & 255)) << (8 * ni);
        }
        *(unsigned int*)&Hq[(size_t)row * 512 + (bxg << 6) + ((l & 15) << 2)] = pk;
      }
    }
}

// ---------------- scans over cnt -> off ---------------------------------------
__global__ __launch_bounds__(1024) void k_scan1(int* __restrict__ cnt,
                                                int* __restrict__ bsum, int N) {
  __shared__ int ws[16];
  const int t = threadIdx.x, g = blockIdx.x * 1024 + t;
  const int lane = t & 63, w = t >> 6;
  int v = (g < N) ? cnt[g] : 0;
#pragma unroll
  for (int o = 1; o < 64; o <<= 1) {
    const int y = __shfl_up(v, o);
    if (lane >= o) v += y;
  }
  if (lane == 63) ws[w] = v;
  __syncthreads();
  if (w == 0) {
    int s = (lane < 16) ? ws[lane] : 0;
#pragma unroll
    for (int o = 1; o < 16; o <<= 1) {
      const int y = __shfl_up(s, o);
      if (lane >= o) s += y;
    }
    if (lane < 16) ws[lane] = s;
  }
  __syncthreads();
  v += (w > 0) ? ws[w - 1] : 0;
  if (g < N) cnt[g] = v;                  // in-place inclusive within chunk
  if (t == 1023) bsum[blockIdx.x] = v;
}

// fused: every block scans bsum locally (nb <= 256), then adds carry
__global__ __launch_bounds__(1024) void k_scan3(const int* __restrict__ part,
                                                const int* __restrict__ bsum,
                                                int* __restrict__ off, int N, int nb) {
  __shared__ int sbuf[256];
  const int t = threadIdx.x;
  if (t < 64) {
    int carry = 0;
    for (int base = 0; base < nb; base += 64) {
      int v = (base + t < nb) ? bsum[base + t] : 0;
#pragma unroll
      for (int o = 1; o < 64; o <<= 1) {
        const int y = __shfl_up(v, o);
        if (t >= o) v += y;
      }
      v += carry;
      if (base + t < nb) sbuf[base + t] = v;
      carry = __shfl(v, 63);
    }
  }
  __syncthreads();
  const int g = blockIdx.x * 1024 + t;
  if (g == 0) off[0] = 0;
  if (g < N) off[g + 1] = part[g] + (blockIdx.x ? sbuf[blockIdx.x - 1] : 0);
}

// ---------------- K3: scatter (no atomics; u16 dst) ---------------------------
__global__ void k_scatter(const int* __restrict__ src, const int* __restrict__ dst,
                          const int* __restrict__ off, const unsigned short* __restrict__ rank,
                          unsigned short* __restrict__ csr_dst, int E) {
  int i = blockIdx.x * blockDim.x + threadIdx.x;
  const int stride = gridDim.x * blockDim.x;
  for (; i < E; i += stride)
    csr_dst[off[src[i]] + rank[i]] = (unsigned short)dst[i];
}

// ---------------- K4: fused softmax + SpMM, int8 + packed 32B side-record -----
__global__ __launch_bounds__(256) void k_spmm(const uint2* __restrict__ Hq2,
    const float4* __restrict__ ssrc4, const unsigned char* __restrict__ rec,
    const int* __restrict__ off, const unsigned short* __restrict__ csr_dst,
    const float* __restrict__ bias, float* __restrict__ out, int N) {
  __shared__ float wbuf[4][8][72];   // [wave][col-block][edge], w[h]*scl[d][b]
  __shared__ int   ibuf[4][64];
  const int wv = threadIdx.x >> 6;
  const int lane = threadIdx.x & 63;
  const int n = (blockIdx.x << 2) + wv;
  if (n >= N) return;                 // wave-private LDS, no barriers
  const int hg = lane >> 4;           // head of this lane
  const int b8 = lane >> 3;           // 64-col block of this lane
  const float4 ss4 = ssrc4[n];
  float den4[4] = {};
  float acc[8] = {};
  const int beg = off[n], end = off[n + 1];
  for (int c0 = beg; c0 < end; c0 += 64) {
    const int cnt = min(64, end - c0);
    if (lane < cnt) {                 // -------- phase A --------
      const int d = csr_dst[c0 + lane];          // coalesced u16
      ibuf[wv][lane] = d << 6;                   // row base in uint2 units
      const float4 sd4 = *(const float4*)&rec[(size_t)d * 32];       // one line:
      const uint4  sc  = *(const uint4*)&rec[(size_t)d * 32 + 16];   // sdst+scales
      float e0 = ss4.x + sd4.x; e0 = fmaxf(e0, ALPHA * e0);
      float e1 = ss4.y + sd4.y; e1 = fmaxf(e1, ALPHA * e1);
      float e2 = ss4.z + sd4.z; e2 = fmaxf(e2, ALPHA * e2);
      float e3 = ss4.w + sd4.w; e3 = fmaxf(e3, ALPHA * e3);
      const float w0 = __expf(e0), w1 = __expf(e1), w2 = __expf(e2), w3 = __expf(e3);
      den4[0] += w0; den4[1] += w1; den4[2] += w2; den4[3] += w3;
      wbuf[wv][0][lane] = w0 * bf_lo(sc.x); wbuf[wv][1][lane] = w0 * bf_hi(sc.x);
      wbuf[wv][2][lane] = w1 * bf_lo(sc.y); wbuf[wv][3][lane] = w1 * bf_hi(sc.y);
      wbuf[wv][4][lane] = w2 * bf_lo(sc.z); wbuf[wv][5][lane] = w2 * bf_hi(sc.z);
      wbuf[wv][6][lane] = w3 * bf_lo(sc.w); wbuf[wv][7][lane] = w3 * bf_hi(sc.w);
    }
#pragma unroll 8
    for (int j = 0; j < cnt; ++j) {   // -------- phase B --------
      const float wgt = wbuf[wv][b8][j];         // LDS broadcast (scaled)
      const int db = ibuf[wv][j];                // LDS broadcast
      const uint2 q = Hq2[db + lane];            // 8B gather, 512B/row/wave
      acc[0] = fmaf(wgt, (float)(char)(q.x),       acc[0]);
      acc[1] = fmaf(wgt, (float)(char)(q.x >> 8),  acc[1]);
      acc[2] = fmaf(wgt, (float)(char)(q.x >> 16), acc[2]);
      acc[3] = fmaf(wgt, (float)(char)(q.x >> 24), acc[3]);
      acc[4] = fmaf(wgt, (float)(char)(q.y),       acc[4]);
      acc[5] = fmaf(wgt, (float)(char)(q.y >> 8),  acc[5]);
      acc[6] = fmaf(wgt, (float)(char)(q.y >> 16), acc[6]);
      acc[7] = fmaf(wgt, (float)(char)(q.y >> 24), acc[7]);
    }
  }
#pragma unroll
  for (int k = 0; k < 4; ++k)
#pragma unroll
    for (int m = 1; m < 64; m <<= 1) den4[k] += __shfl_xor(den4[k], m);
  const float r = 1.f / (den4[hg] + EPS);
#pragma unroll
  for (int i = 0; i < 8; ++i) acc[i] *= r;
#pragma unroll
  for (int i = 0; i < 8; ++i) {       // sum the 4 heads (same feature at l^16,l^32)
    acc[i] += __shfl_xor(acc[i], 16);
    acc[i] += __shfl_xor(acc[i], 32);
  }
  if (lane < 16) {
    // permuted layout: acc[i] = feature 64*((lane>>3)&1) + (i&3)*16 + 2*(lane&7) + (i>>2)
    const int base = ((lane >> 3) & 1) * 64 + ((lane & 7) << 1);
#pragma unroll
    for (int k = 0; k < 4; ++k) {
      const float2 b2 = *(const float2*)&bias[base + k * 16];
      *(float2*)&out[(size_t)n * F_OUT + base + k * 16] =
          make_float2(0.25f * acc[k] + b2.x, 0.25f * acc[k + 4] + b2.y);
    }
  }
}

// ---------------- launch -------------------------------------------------------
extern "C" void kernel_launch(void* const* d_in, const int* in_sizes, int n_in,
                              void* d_out, int out_size, void* d_ws, size_t ws_size,
                              hipStream_t stream) {
  const float* H    = (const float*)d_in[0];
  const int*   ei   = (const int*)d_in[1];
  const float* W    = (const float*)d_in[2];   // [4,128,256] == [512,256]
  const float* a    = (const float*)d_in[3];   // [4,256]
  const float* bias = (const float*)d_in[4];   // [128]
  const int N = in_sizes[0] / F_IN;
  const int E = in_sizes[1] / 2;
  const int* src = ei;
  const int* dst = ei + E;

  char* ws = (char*)d_ws;
  size_t o = 0;
  auto alloc = [&](size_t bytes) -> void* {
    void* p = ws + o;
    o = (o + bytes + 255) & ~(size_t)255;
    return p;
  };
  unsigned short* Hb  = (unsigned short*)alloc((size_t)N * F_IN * 2);   // 25.6 MB bf16 H
  unsigned short* Wb  = (unsigned short*)alloc((size_t)COLS * F_IN * 2);
  unsigned char*  Hq  = (unsigned char*)alloc((size_t)N * COLS);        // 25.6 MB int8
  float* uvec = (float*)alloc(8 * F_IN * sizeof(float));
  float* ssrc = (float*)alloc((size_t)N * HEADS * sizeof(float));
  unsigned char* rec = (unsigned char*)alloc((size_t)N * 32);           // 1.6 MB packed
  int*   cnt  = (int*)alloc((size_t)N * sizeof(int));
  int*   off  = (int*)alloc(((size_t)N + 1) * sizeof(int));
  unsigned short* csr = (unsigned short*)alloc((size_t)E * sizeof(unsigned short));
  unsigned short* rank = (unsigned short*)alloc((size_t)E * sizeof(unsigned short));
  const int nb = (N + 1023) / 1024;
  int*   bsum = (int*)alloc((size_t)nb * sizeof(int));

  hipMemsetAsync(cnt, 0, (size_t)N * sizeof(int), stream);

  k_wprep<<<136, 256, 0, stream>>>(W, a, Wb, uvec);
  const int CB = (N + 3) / 4;
  k_pre<<<CB + 1024, 256, 0, stream>>>((const float4*)H, uvec, Hb,
                                       (float4*)ssrc, rec, N, CB,
                                       src, cnt, rank, E);
  dim3 ggrid(COLS / 128, (N + 127) / 128);
  k_gemm_q<<<ggrid, 256, 0, stream>>>(Hb, Wb, Hq, rec, N);
  k_scan1<<<nb, 1024, 0, stream>>>(cnt, bsum, N);
  k_scan3<<<nb, 1024, 0, stream>>>(cnt, bsum, off, N, nb);
  k_scatter<<<1024, 256, 0, stream>>>(src, dst, off, rank, csr, E);
  k_spmm<<<(N + 3) / 4, 256, 0, stream>>>((const uint2*)Hq, (const float4*)ssrc,
                                          rec, off, csr, bias, (float*)d_out, N);
}

// Round 8
// 300.779 us; speedup vs baseline: 2.9728x; 1.0002x over previous
//
#include <hip/hip_runtime.h>

#define ALPHA 0.2f
#define EPS 1e-16f

static constexpr int F_IN = 256;
static constexpr int F_OUT = 128;
static constexpr int HEADS = 4;
static constexpr int COLS = HEADS * F_OUT; // 512

typedef __bf16 bf16x8 __attribute__((ext_vector_type(8)));
typedef float f32x4 __attribute__((ext_vector_type(4)));

static __device__ __forceinline__ unsigned short f2bf(float f) {
  unsigned int u = __float_as_uint(f);
  unsigned int r = (u + 0x7FFFu + ((u >> 16) & 1u)) >> 16;  // RN-even
  return (unsigned short)r;
}
static __device__ __forceinline__ float bf_lo(unsigned int u) {
  return __uint_as_float(u << 16);
}
static __device__ __forceinline__ float bf_hi(unsigned int u) {
  return __uint_as_float(u & 0xFFFF0000u);
}

// ---------------- K0: W cast to bf16 (blocks 0..127) + uvec (blocks 128..135) --
__global__ __launch_bounds__(256) void k_wprep(const float* __restrict__ W,
                                               const float* __restrict__ a,
                                               unsigned short* __restrict__ Wb,
                                               float* __restrict__ u) {
  if (blockIdx.x < 128) {
    const int i = blockIdx.x * 256 + threadIdx.x;   // n4 = 512*256/4 = 32768
    const float4 v = ((const float4*)W)[i];
    ((ushort4*)Wb)[i] = make_ushort4(f2bf(v.x), f2bf(v.y), f2bf(v.z), f2bf(v.w));
  } else {
    const int b = blockIdx.x - 128;  // 0..7 = h*2+dual
    const int h = b >> 1, dual = b & 1;
    const int k = threadIdx.x;
    float s = 0.f;
    for (int f = 0; f < F_OUT; ++f)
      s = fmaf(a[h * 2 * F_OUT + dual * F_OUT + f], W[((size_t)h * F_OUT + f) * F_IN + k], s);
    u[b * F_IN + k] = s;
  }
}

// ---------------- K1: fused H cast + scores (blocks < CB) + edge rank (rest) --
// rec[n] (32B): bytes 0..15 = sdst (4 f32); bytes 16..31 = 8 bf16 scales (by gemm)
__global__ __launch_bounds__(256) void k_pre(const float4* __restrict__ H4,
    const float* __restrict__ u, unsigned short* __restrict__ Hb,
    float4* __restrict__ ssrc4, unsigned char* __restrict__ rec, int N, int CB,
    const int* __restrict__ src, int* __restrict__ cnt,
    unsigned short* __restrict__ rank, int E) {
  if ((int)blockIdx.x >= CB) {  // ---- edge rank pass (1024 blocks) ----
    int i = (blockIdx.x - CB) * 256 + threadIdx.x;
    const int stride = 1024 * 256;
    for (; i < E; i += stride) rank[i] = (unsigned short)atomicAdd(&cnt[src[i]], 1);
    return;
  }
  const int wv = threadIdx.x >> 6, lane = threadIdx.x & 63;
  const int n = ((int)blockIdx.x << 2) + wv;
  if (n >= N) return;
  const float4 hv = H4[(size_t)n * 64 + lane];
  *((ushort4*)(Hb + (size_t)n * F_IN) + lane) =
      make_ushort4(f2bf(hv.x), f2bf(hv.y), f2bf(hv.z), f2bf(hv.w));
  float p[8];
#pragma unroll
  for (int c = 0; c < 8; ++c) {
    const float4 uv = *(const float4*)&u[c * F_IN + (lane << 2)];
    p[c] = fmaf(hv.x, uv.x, fmaf(hv.y, uv.y, fmaf(hv.z, uv.z, hv.w * uv.w)));
  }
#pragma unroll
  for (int c = 0; c < 8; ++c)
#pragma unroll
    for (int m = 1; m < 64; m <<= 1) p[c] += __shfl_xor(p[c], m);
  if (lane == 0) {
    ssrc4[n] = make_float4(p[0], p[2], p[4], p[6]);
    *(float4*)&rec[(size_t)n * 32] = make_float4(p[1], p[3], p[5], p[7]);
  }
}

// ---------------- K2: 128x128 MFMA GEMM, int8(excess-128) quant epilogue ------
// XCD-chunked 1D grid (bijective, m204): each XCD gets consecutive (row,col)
// pairs with col fastest -> the 64KB A row-tile is L2-resident across its
// 4 col-blocks on that XCD.
// Hq row layout (per 64-col block b): u32 at byte 64b+4k holds cols {0,16,32,48}+k,
// each byte = q+128 (excess-128 unsigned).
__global__ __launch_bounds__(256) void k_gemm_q(const unsigned short* __restrict__ A,
                                                const unsigned short* __restrict__ B,
                                                unsigned char* __restrict__ Hq,
                                                unsigned char* __restrict__ rec, int N) {
  __shared__ __bf16 As[128][40];
  __shared__ __bf16 Bs[128][40];
  // --- bijective XCD chunking of the 1D grid ---
  const int T = gridDim.x;
  const int q8 = T >> 3, r8 = T & 7;
  const int xcd = blockIdx.x & 7, ii = blockIdx.x >> 3;
  const int gp = (xcd < r8) ? xcd * (q8 + 1) + ii
                            : r8 * (q8 + 1) + (xcd - r8) * q8 + ii;
  const int by = gp >> 2;                  // row-tile
  const int bx = gp & 3;                   // 128-col block
  const int t = threadIdx.x;
  const int w = t >> 6, l = t & 63;
  const int wr = w >> 1, wc = w & 1;       // 2x2 wave grid, each 64x64
  const int m0 = by << 7, n0 = bx << 7;
  const int lr = t >> 1, seg16 = (t & 1) << 4;   // staging: row 0..127, col 0/16
  f32x4 acc[4][4] = {};
  for (int k0 = 0; k0 < F_IN; k0 += 32) {
    int ar = m0 + lr; if (ar >= N) ar = N - 1;   // clamp; stores guarded
    const uint4 a0 = *(const uint4*)&A[(size_t)ar * F_IN + k0 + seg16];
    const uint4 a1 = *(const uint4*)&A[(size_t)ar * F_IN + k0 + seg16 + 8];
    const uint4 b0 = *(const uint4*)&B[(size_t)(n0 + lr) * F_IN + k0 + seg16];
    const uint4 b1 = *(const uint4*)&B[(size_t)(n0 + lr) * F_IN + k0 + seg16 + 8];
    __syncthreads();
    *(uint4*)&As[lr][seg16] = a0;  *(uint4*)&As[lr][seg16 + 8] = a1;
    *(uint4*)&Bs[lr][seg16] = b0;  *(uint4*)&Bs[lr][seg16 + 8] = b1;
    __syncthreads();
    const int kb = (l >> 4) << 3;
    bf16x8 af[4], bf_[4];
#pragma unroll
    for (int mi = 0; mi < 4; ++mi)
      af[mi] = *(const bf16x8*)&As[(wr << 6) + (mi << 4) + (l & 15)][kb];
#pragma unroll
    for (int ni = 0; ni < 4; ++ni)
      bf_[ni] = *(const bf16x8*)&Bs[(wc << 6) + (ni << 4) + (l & 15)][kb];
#pragma unroll
    for (int mi = 0; mi < 4; ++mi)
#pragma unroll
      for (int ni = 0; ni < 4; ++ni)
        acc[mi][ni] = __builtin_amdgcn_mfma_f32_16x16x32_bf16(af[mi], bf_[ni], acc[mi][ni], 0, 0, 0);
  }
  const int bxg = (bx << 1) + wc;          // global 64-col block 0..7
#pragma unroll
  for (int mi = 0; mi < 4; ++mi)
#pragma unroll
    for (int r = 0; r < 4; ++r) {
      float mx = 0.f;
#pragma unroll
      for (int ni = 0; ni < 4; ++ni) mx = fmaxf(mx, fabsf(acc[mi][ni][r]));
#pragma unroll
      for (int m = 1; m < 16; m <<= 1) mx = fmaxf(mx, __shfl_xor(mx, m));
      const int row = m0 + (wr << 6) + (mi << 4) + ((l >> 4) << 2) + r;
      if (row < N) {
        const float inv = (mx > 0.f) ? 127.f / mx : 0.f;
        if ((l & 15) == 0)
          *(unsigned short*)&rec[(size_t)row * 32 + 16 + (bxg << 1)] = f2bf(mx * (1.f / 127.f));
        unsigned int pk = 0;
#pragma unroll
        for (int ni = 0; ni < 4; ++ni) {
          float tq = fminf(fmaxf(rintf(acc[mi][ni][r] * inv), -127.f), 127.f);
          pk |= ((unsigned int)(((int)tq + 128) & 255)) << (8 * ni);  // excess-128
        }
        *(unsigned int*)&Hq[(size_t)row * 512 + (bxg << 6) + ((l & 15) << 2)] = pk;
      }
    }
}

// ---------------- scans over cnt -> off ---------------------------------------
__global__ __launch_bounds__(1024) void k_scan1(int* __restrict__ cnt,
                                                int* __restrict__ bsum, int N) {
  __shared__ int ws[16];
  const int t = threadIdx.x, g = blockIdx.x * 1024 + t;
  const int lane = t & 63, w = t >> 6;
  int v = (g < N) ? cnt[g] : 0;
#pragma unroll
  for (int o = 1; o < 64; o <<= 1) {
    const int y = __shfl_up(v, o);
    if (lane >= o) v += y;
  }
  if (lane == 63) ws[w] = v;
  __syncthreads();
  if (w == 0) {
    int s = (lane < 16) ? ws[lane] : 0;
#pragma unroll
    for (int o = 1; o < 16; o <<= 1) {
      const int y = __shfl_up(s, o);
      if (lane >= o) s += y;
    }
    if (lane < 16) ws[lane] = s;
  }
  __syncthreads();
  v += (w > 0) ? ws[w - 1] : 0;
  if (g < N) cnt[g] = v;                  // in-place inclusive within chunk
  if (t == 1023) bsum[blockIdx.x] = v;
}

// fused: every block scans bsum locally (nb <= 256), then adds carry
__global__ __launch_bounds__(1024) void k_scan3(const int* __restrict__ part,
                                                const int* __restrict__ bsum,
                                                int* __restrict__ off, int N, int nb) {
  __shared__ int sbuf[256];
  const int t = threadIdx.x;
  if (t < 64) {
    int carry = 0;
    for (int base = 0; base < nb; base += 64) {
      int v = (base + t < nb) ? bsum[base + t] : 0;
#pragma unroll
      for (int o = 1; o < 64; o <<= 1) {
        const int y = __shfl_up(v, o);
        if (t >= o) v += y;
      }
      v += carry;
      if (base + t < nb) sbuf[base + t] = v;
      carry = __shfl(v, 63);
    }
  }
  __syncthreads();
  const int g = blockIdx.x * 1024 + t;
  if (g == 0) off[0] = 0;
  if (g < N) off[g + 1] = part[g] + (blockIdx.x ? sbuf[blockIdx.x - 1] : 0);
}

// ---------------- K3: scatter (no atomics; u16 dst) ---------------------------
__global__ void k_scatter(const int* __restrict__ src, const int* __restrict__ dst,
                          const int* __restrict__ off, const unsigned short* __restrict__ rank,
                          unsigned short* __restrict__ csr_dst, int E) {
  int i = blockIdx.x * blockDim.x + threadIdx.x;
  const int stride = gridDim.x * blockDim.x;
  for (; i < E; i += stride)
    csr_dst[off[src[i]] + rank[i]] = (unsigned short)dst[i];
}

// ---------------- K4: fused softmax + SpMM, excess-128 int8 -------------------
__global__ __launch_bounds__(256) void k_spmm(const uint2* __restrict__ Hq2,
    const float4* __restrict__ ssrc4, const unsigned char* __restrict__ rec,
    const int* __restrict__ off, const unsigned short* __restrict__ csr_dst,
    const float* __restrict__ bias, float* __restrict__ out, int N) {
  __shared__ float wbuf[4][8][72];   // [wave][col-block][edge], w[h]*scl[d][b]
  __shared__ int   ibuf[4][64];
  const int wv = threadIdx.x >> 6;
  const int lane = threadIdx.x & 63;
  const int n = (blockIdx.x << 2) + wv;
  if (n >= N) return;                 // wave-private LDS, no barriers
  const int hg = lane >> 4;           // head of this lane
  const int b8 = lane >> 3;           // 64-col block of this lane
  const float4 ss4 = ssrc4[n];
  float den4[4] = {};
  float acc[8] = {};
  float sw = 0.f;                     // sum of this lane's scaled weights
  const int beg = off[n], end = off[n + 1];
  for (int c0 = beg; c0 < end; c0 += 64) {
    const int cnt = min(64, end - c0);
    if (lane < cnt) {                 // -------- phase A --------
      const int d = csr_dst[c0 + lane];          // coalesced u16
      ibuf[wv][lane] = d << 6;                   // row base in uint2 units
      const float4 sd4 = *(const float4*)&rec[(size_t)d * 32];       // one line:
      const uint4  sc  = *(const uint4*)&rec[(size_t)d * 32 + 16];   // sdst+scales
      float e0 = ss4.x + sd4.x; e0 = fmaxf(e0, ALPHA * e0);
      float e1 = ss4.y + sd4.y; e1 = fmaxf(e1, ALPHA * e1);
      float e2 = ss4.z + sd4.z; e2 = fmaxf(e2, ALPHA * e2);
      float e3 = ss4.w + sd4.w; e3 = fmaxf(e3, ALPHA * e3);
      const float w0 = __expf(e0), w1 = __expf(e1), w2 = __expf(e2), w3 = __expf(e3);
      den4[0] += w0; den4[1] += w1; den4[2] += w2; den4[3] += w3;
      wbuf[wv][0][lane] = w0 * bf_lo(sc.x); wbuf[wv][1][lane] = w0 * bf_hi(sc.x);
      wbuf[wv][2][lane] = w1 * bf_lo(sc.y); wbuf[wv][3][lane] = w1 * bf_hi(sc.y);
      wbuf[wv][4][lane] = w2 * bf_lo(sc.z); wbuf[wv][5][lane] = w2 * bf_hi(sc.z);
      wbuf[wv][6][lane] = w3 * bf_lo(sc.w); wbuf[wv][7][lane] = w3 * bf_hi(sc.w);
    }
#pragma unroll 8
    for (int j = 0; j < cnt; ++j) {   // -------- phase B --------
      const float wgt = wbuf[wv][b8][j];         // LDS broadcast (scaled)
      const int db = ibuf[wv][j];                // LDS broadcast
      const uint2 q = Hq2[db + lane];            // 8B gather, 512B/row/wave
      sw += wgt;
      // excess-128 bytes -> v_cvt_f32_ubyte{0..3}
      acc[0] = fmaf(wgt, (float)(q.x & 0xffu),         acc[0]);
      acc[1] = fmaf(wgt, (float)((q.x >> 8) & 0xffu),  acc[1]);
      acc[2] = fmaf(wgt, (float)((q.x >> 16) & 0xffu), acc[2]);
      acc[3] = fmaf(wgt, (float)(q.x >> 24),           acc[3]);
      acc[4] = fmaf(wgt, (float)(q.y & 0xffu),         acc[4]);
      acc[5] = fmaf(wgt, (float)((q.y >> 8) & 0xffu),  acc[5]);
      acc[6] = fmaf(wgt, (float)((q.y >> 16) & 0xffu), acc[6]);
      acc[7] = fmaf(wgt, (float)(q.y >> 24),           acc[7]);
    }
  }
#pragma unroll
  for (int k = 0; k < 4; ++k)
#pragma unroll
    for (int m = 1; m < 64; m <<= 1) den4[k] += __shfl_xor(den4[k], m);
  const float r = 1.f / (den4[hg] + EPS);
  const float corr = 128.f * sw;      // undo excess-128 bias
#pragma unroll
  for (int i = 0; i < 8; ++i) acc[i] = (acc[i] - corr) * r;
#pragma unroll
  for (int i = 0; i < 8; ++i) {       // sum the 4 heads (same feature at l^16,l^32)
    acc[i] += __shfl_xor(acc[i], 16);
    acc[i] += __shfl_xor(acc[i], 32);
  }
  if (lane < 16) {
    // permuted layout: acc[i] = feature 64*((lane>>3)&1) + (i&3)*16 + 2*(lane&7) + (i>>2)
    const int base = ((lane >> 3) & 1) * 64 + ((lane & 7) << 1);
#pragma unroll
    for (int k = 0; k < 4; ++k) {
      const float2 b2 = *(const float2*)&bias[base + k * 16];
      *(float2*)&out[(size_t)n * F_OUT + base + k * 16] =
          make_float2(0.25f * acc[k] + b2.x, 0.25f * acc[k + 4] + b2.y);
    }
  }
}

// ---------------- launch -------------------------------------------------------
extern "C" void kernel_launch(void* const* d_in, const int* in_sizes, int n_in,
                              void* d_out, int out_size, void* d_ws, size_t ws_size,
                              hipStream_t stream) {
  const float* H    = (const float*)d_in[0];
  const int*   ei   = (const int*)d_in[1];
  const float* W    = (const float*)d_in[2];   // [4,128,256] == [512,256]
  const float* a    = (const float*)d_in[3];   // [4,256]
  const float* bias = (const float*)d_in[4];   // [128]
  const int N = in_sizes[0] / F_IN;
  const int E = in_sizes[1] / 2;
  const int* src = ei;
  const int* dst = ei + E;

  char* ws = (char*)d_ws;
  size_t o = 0;
  auto alloc = [&](size_t bytes) -> void* {
    void* p = ws + o;
    o = (o + bytes + 255) & ~(size_t)255;
    return p;
  };
  unsigned short* Hb  = (unsigned short*)alloc((size_t)N * F_IN * 2);   // 25.6 MB bf16 H
  unsigned short* Wb  = (unsigned short*)alloc((size_t)COLS * F_IN * 2);
  unsigned char*  Hq  = (unsigned char*)alloc((size_t)N * COLS);        // 25.6 MB int8
  float* uvec = (float*)alloc(8 * F_IN * sizeof(float));
  float* ssrc = (float*)alloc((size_t)N * HEADS * sizeof(float));
  unsigned char* rec = (unsigned char*)alloc((size_t)N * 32);           // 1.6 MB packed
  int*   cnt  = (int*)alloc((size_t)N * sizeof(int));
  int*   off  = (int*)alloc(((size_t)N + 1) * sizeof(int));
  unsigned short* csr = (unsigned short*)alloc((size_t)E * sizeof(unsigned short));
  unsigned short* rank = (unsigned short*)alloc((size_t)E * sizeof(unsigned short));
  const int nb = (N + 1023) / 1024;
  int*   bsum = (int*)alloc((size_t)nb * sizeof(int));

  hipMemsetAsync(cnt, 0, (size_t)N * sizeof(int), stream);

  k_wprep<<<136, 256, 0, stream>>>(W, a, Wb, uvec);
  const int CB = (N + 3) / 4;
  k_pre<<<CB + 1024, 256, 0, stream>>>((const float4*)H, uvec, Hb,
                                       (float4*)ssrc, rec, N, CB,
                                       src, cnt, rank, E);
  const int nb128 = (N + 127) / 128;
  k_gemm_q<<<4 * nb128, 256, 0, stream>>>(Hb, Wb, Hq, rec, N);
  k_scan1<<<nb, 1024, 0, stream>>>(cnt, bsum, N);
  k_scan3<<<nb, 1024, 0, stream>>>(cnt, bsum, off, N, nb);
  k_scatter<<<1024, 256, 0, stream>>>(src, dst, off, rank, csr, E);
  k_spmm<<<(N + 3) / 4, 256, 0, stream>>>((const uint2*)Hq, (const float4*)ssrc,
                                          rec, off, csr, bias, (float*)d_out, N);
}